// Round 2
// baseline (524.208 us; speedup 1.0000x reference)
//
#include <hip/hip_runtime.h>

// ---------------- dtype-adaptive accessors ----------------

__device__ __forceinline__ float ldf(const void* p, long long i, int f32) {
    if (f32) return ((const float*)p)[i];
    unsigned int u = ((const unsigned short*)p)[i];
    return __uint_as_float(u << 16);
}
__device__ __forceinline__ int ld_idx(const int* p, long long i, int i64) {
    return i64 ? p[2 * i] : p[i];   // little-endian low word of int64
}
__device__ __forceinline__ unsigned short f2bf(float v) {
    unsigned int x = __float_as_uint(v);
    return (unsigned short)((x + 0x7FFFu + ((x >> 16) & 1u)) >> 16);  // RNE
}
__device__ __forceinline__ int clampi(int v, int lo, int hi) {
    return v < lo ? lo : (v > hi ? hi : v);
}

// ---------------- dtype detection ----------------
// flags[0] = 1 if float tensors are f32, 0 if bf16
// flags[1] = 1 if int tensors are int64, 0 if int32

__global__ void gnn_detect(const unsigned int* __restrict__ w1_words,
                           const int* __restrict__ ei_words,
                           int* __restrict__ flags) {
    __shared__ int cnt;
    __shared__ int orred;
    int t = threadIdx.x;
    if (t == 0) { cnt = 0; orred = 0; }
    __syncthreads();
    int c = 0, o = 0;
    for (int i = t; i < 512; i += 256) {
        unsigned int e = (w1_words[i] >> 7) & 0xFFu;   // bf16-packed: low elem's exponent
        if (e >= 100 && e <= 140) c++;
    }
    for (int i = t; i < 4096; i += 256) o |= ei_words[2 * i + 1];  // int64: high words all 0
    atomicAdd(&cnt, c);
    atomicOr(&orred, o);
    __syncthreads();
    if (t == 0) {
        flags[0] = (cnt > 256) ? 0 : 1;   // many hits -> bf16
        flags[1] = (orred == 0) ? 1 : 0;  // all-zero high words -> int64
    }
}

// ---------------- utilities ----------------

__global__ void gnn_zero(unsigned int* __restrict__ p, int n) {
    int i = blockIdx.x * blockDim.x + threadIdx.x;
    if (i < n) p[i] = 0u;
}

// convert all weight tensors to one contiguous f32 region
#define OW1 0
#define OB1 8192
#define OW2 8320
#define OB2 24704
#define OW3 24832
#define OB3 41216
#define OW4 41344
#define OB4 49536
#define OTOT 49600

__global__ void gnn_convert_w(const void* W1, const void* b1, const void* W2, const void* b2,
                              const void* W3, const void* b3, const void* W4, const void* b4,
                              const int* __restrict__ flags, float* __restrict__ dst) {
    int f32 = flags[0];
    int i = blockIdx.x * blockDim.x + threadIdx.x;
    if (i >= OTOT) return;
    float v;
    if      (i < OB1) v = ldf(W1, i - OW1, f32);
    else if (i < OW2) v = ldf(b1, i - OB1, f32);
    else if (i < OB2) v = ldf(W2, i - OW2, f32);
    else if (i < OW3) v = ldf(b2, i - OB2, f32);
    else if (i < OB3) v = ldf(W3, i - OW3, f32);
    else if (i < OW4) v = ldf(b3, i - OB3, f32);
    else if (i < OB4) v = ldf(W4, i - OW4, f32);
    else              v = ldf(b4, i - OB4, f32);
    dst[i] = v;
}

// ---------------- CSR build ----------------

__global__ void gnn_hist(const int* __restrict__ ei, int E, int N,
                         const int* __restrict__ flags, int* __restrict__ degcnt) {
    int e = blockIdx.x * blockDim.x + threadIdx.x;
    if (e >= E) return;
    int i64 = flags[1];
    int d = clampi(ld_idx(ei, (long long)E + e, i64), 0, N - 1);
    atomicAdd(&degcnt[d], 1);
}

__global__ void gnn_dis(const int* __restrict__ degcnt, float* __restrict__ dis, int N) {
    int i = blockIdx.x * blockDim.x + threadIdx.x;
    if (i < N) dis[i] = rsqrtf((float)degcnt[i] + 1.0f);  // +1 self-loop
}

// three-pass exclusive scan: per-block scan -> scan of block sums -> add offsets
__global__ void gnn_scan1(const int* __restrict__ cnt, int* __restrict__ excl,
                          int* __restrict__ sums, int N) {
    __shared__ int sh[256];
    int t = threadIdx.x;
    int i = blockIdx.x * 256 + t;
    int v = (i < N) ? cnt[i] : 0;
    sh[t] = v;
    __syncthreads();
    for (int off = 1; off < 256; off <<= 1) {
        int a = (t >= off) ? sh[t - off] : 0;
        __syncthreads();
        sh[t] += a;
        __syncthreads();
    }
    if (i < N) excl[i] = sh[t] - v;
    if (t == 255) sums[blockIdx.x] = sh[255];
}

__global__ void gnn_scan2(int* __restrict__ sums, int nb) {
    __shared__ int sh[256];
    int t = threadIdx.x;
    int v = (t < nb) ? sums[t] : 0;
    sh[t] = v;
    __syncthreads();
    for (int off = 1; off < 256; off <<= 1) {
        int a = (t >= off) ? sh[t - off] : 0;
        __syncthreads();
        sh[t] += a;
        __syncthreads();
    }
    if (t < nb) sums[t] = sh[t] - v;  // exclusive over block sums
}

__global__ void gnn_scan3(int* __restrict__ row_ptr, const int* __restrict__ sums,
                          int N, int E) {
    int i = blockIdx.x * 256 + threadIdx.x;
    if (i < N) row_ptr[i] += sums[blockIdx.x];
    if (i == 0) row_ptr[N] = E;   // total degree = E by construction
}

__global__ void gnn_fill(const int* __restrict__ ei, const float* __restrict__ dis,
                         const int* __restrict__ row_ptr, int* __restrict__ fillcnt,
                         int* __restrict__ csr_src, float* __restrict__ csr_norm,
                         int E, int N, const int* __restrict__ flags) {
    int e = blockIdx.x * blockDim.x + threadIdx.x;
    if (e >= E) return;
    int i64 = flags[1];
    int s = clampi(ld_idx(ei, (long long)e, i64), 0, N - 1);
    int d = clampi(ld_idx(ei, (long long)E + e, i64), 0, N - 1);
    int pos = row_ptr[d] + atomicAdd(&fillcnt[d], 1);
    csr_src[pos] = s;
    csr_norm[pos] = dis[s] * dis[d];
}

// ---------------- Linear: out[N,128] = X[N,K] @ W[K,128], f32 accumulate ----------------
// 8 nodes/block, 256 threads = (half, feature)

__global__ __launch_bounds__(256) void gnn_linear(const void* __restrict__ X,
                                                  const float* __restrict__ Wf,
                                                  int K, int N, const int* __restrict__ flags,
                                                  int force_f32, float* __restrict__ out) {
    __shared__ float Wl[64 * 128];
    __shared__ float Xs[8 * 128];
    const int xf32 = force_f32 ? 1 : flags[0];
    const int t = threadIdx.x;
    const int nbase = blockIdx.x * 8;

    for (int i = t; i < 8 * K; i += 256) {
        int nn = i / K, kk = i - nn * K;
        int n = nbase + nn;
        Xs[i] = (n < N) ? ldf(X, (long long)n * K + kk, xf32) : 0.0f;
    }

    const int f = t & 127;
    const int half = t >> 7;
    float acc[4] = {0.f, 0.f, 0.f, 0.f};

    for (int kc = 0; kc < K; kc += 64) {
        __syncthreads();
        for (int i = t; i < 64 * 128; i += 256)
            Wl[i] = Wf[(kc + (i >> 7)) * 128 + (i & 127)];
        __syncthreads();
#pragma unroll 8
        for (int k = 0; k < 64; ++k) {
            float w = Wl[k * 128 + f];
            int kk = kc + k;
#pragma unroll
            for (int j = 0; j < 4; ++j)
                acc[j] += Xs[(half * 4 + j) * K + kk] * w;
        }
    }
#pragma unroll
    for (int j = 0; j < 4; ++j) {
        int n = nbase + half * 4 + j;
        if (n < N) out[(long long)n * 128 + f] = acc[j];
    }
}

// ---------------- Aggregate: out[n,:] = relu(sum_e norm*lin[src] + dis[n]^2*lin[n] + bias) ----

__global__ __launch_bounds__(128) void gnn_aggregate(const float* __restrict__ lin,
                                                     const int* __restrict__ row_ptr,
                                                     const int* __restrict__ csr_src,
                                                     const float* __restrict__ csr_norm,
                                                     const float* __restrict__ dis,
                                                     const float* __restrict__ bias,
                                                     float* __restrict__ out, int N) {
    int n = blockIdx.x;
    if (n >= N) return;
    int f = threadIdx.x;
    int beg = row_ptr[n], end = row_ptr[n + 1];
    float dn = dis[n];
    float acc = lin[(long long)n * 128 + f] * (dn * dn);   // self-loop term
    for (int e = beg; e < end; ++e) {
        int s = csr_src[e];          // wave-uniform broadcast
        float w = csr_norm[e];
        acc += w * lin[(long long)s * 128 + f];            // coalesced 512B row gather
    }
    acc += bias[f];
    out[(long long)n * 128 + f] = fmaxf(acc, 0.0f);
}

// ---------------- Pool (batch sorted): local accumulate, flush on segment change ------------

__global__ __launch_bounds__(128) void gnn_pool(const float* __restrict__ h,
                                                const int* __restrict__ batch,
                                                const int* __restrict__ flags,
                                                float* __restrict__ pooled,
                                                float* __restrict__ cntf, int N, int B) {
    int i64 = flags[1];
    int f = threadIdx.x;
    int n0 = blockIdx.x * 128;
    if (n0 >= N) return;
    int nend = min(n0 + 128, N);
    int cur = clampi(ld_idx(batch, n0, i64), 0, B - 1);
    float acc = 0.0f;
    int cc = 0;
    for (int n = n0; n < nend; ++n) {
        int b = clampi(ld_idx(batch, n, i64), 0, B - 1);   // wave-uniform
        if (b != cur) {
            atomicAdd(&pooled[cur * 128 + f], acc);
            if (f == 0) atomicAdd(&cntf[cur], (float)cc);
            acc = 0.0f; cc = 0; cur = b;
        }
        acc += h[(long long)n * 128 + f];
        ++cc;
    }
    atomicAdd(&pooled[cur * 128 + f], acc);
    if (f == 0) atomicAdd(&cntf[cur], (float)cc);
}

// ---------------- Head ----------------

__global__ __launch_bounds__(128) void gnn_head1(const float* __restrict__ pooled,
                                                 const float* __restrict__ cntf,
                                                 const float* __restrict__ W3,
                                                 const float* __restrict__ b3,
                                                 float* __restrict__ r) {
    __shared__ float xs[128];
    int b = blockIdx.x, f = threadIdx.x;
    float c = fmaxf(cntf[b], 1.0f);
    xs[f] = pooled[b * 128 + f] / c;
    __syncthreads();
    float acc = b3[f];
    for (int k = 0; k < 128; ++k) acc += xs[k] * W3[k * 128 + f];
    r[b * 128 + f] = fmaxf(acc, 0.0f);
}

__global__ __launch_bounds__(64) void gnn_head2(const float* __restrict__ r,
                                                const float* __restrict__ W4,
                                                const float* __restrict__ b4,
                                                const int* __restrict__ flags,
                                                void* __restrict__ outv) {
    __shared__ float xs[128];
    int b = blockIdx.x, f = threadIdx.x;
    xs[f] = r[b * 128 + f];
    xs[f + 64] = r[b * 128 + f + 64];
    __syncthreads();
    float acc = b4[f];
    for (int k = 0; k < 128; ++k) acc += xs[k] * W4[k * 64 + f];
    if (flags[0]) ((float*)outv)[b * 64 + f] = acc;
    else          ((unsigned short*)outv)[b * 64 + f] = f2bf(acc);
}

// ---------------- Launch ----------------

extern "C" void kernel_launch(void* const* d_in, const int* in_sizes, int n_in,
                              void* d_out, int out_size, void* d_ws, size_t ws_size,
                              hipStream_t stream) {
    const void* x  = d_in[0];
    const int* ei  = (const int*)d_in[1];
    const int* bat = (const int*)d_in[2];

    const int N = in_sizes[0] / 64;    // 50000
    const int E = in_sizes[1] / 2;     // 800000
    const int B = out_size / 64;       // 64

    // workspace carve-up (256B aligned)
    char* p = (char*)d_ws;
    auto alloc = [&](size_t bytes) { void* q = (void*)p; p += (bytes + 255) & ~(size_t)255; return q; };
    int*   flags    = (int*)alloc(256);
    float* wsW      = (float*)alloc((size_t)OTOT * 4);
    int*   degcnt   = (int*)alloc((size_t)N * 4);
    int*   fillcnt  = (int*)alloc((size_t)N * 4);
    float* dis      = (float*)alloc((size_t)N * 4);
    int*   row_ptr  = (int*)alloc((size_t)(N + 1) * 4);
    int*   sums     = (int*)alloc(1024);
    int*   csr_src  = (int*)alloc((size_t)E * 4);
    float* csr_norm = (float*)alloc((size_t)E * 4);
    float* A        = (float*)alloc((size_t)N * 128 * 4);
    float* C        = (float*)alloc((size_t)N * 128 * 4);
    float* pooled   = (float*)alloc((size_t)B * 128 * 4);
    float* cntf     = (float*)alloc((size_t)B * 4);
    float* r        = (float*)alloc((size_t)B * 128 * 4);
    (void)ws_size; (void)n_in;

    const int nbN = (N + 255) / 256;   // 196 (fits single-block scan2)

    // 0) dtype detection + zero-init + weight conversion
    gnn_detect<<<1, 256, 0, stream>>>((const unsigned int*)d_in[3], ei, flags);
    gnn_zero<<<nbN, 256, 0, stream>>>((unsigned int*)degcnt, N);
    gnn_zero<<<nbN, 256, 0, stream>>>((unsigned int*)fillcnt, N);
    gnn_zero<<<(B * 128 + 255) / 256, 256, 0, stream>>>((unsigned int*)pooled, B * 128);
    gnn_zero<<<1, 256, 0, stream>>>((unsigned int*)cntf, B);
    gnn_convert_w<<<(OTOT + 255) / 256, 256, 0, stream>>>(d_in[3], d_in[4], d_in[5], d_in[6],
                                                          d_in[7], d_in[8], d_in[9], d_in[10],
                                                          flags, wsW);

    // 1) CSR build
    gnn_hist<<<(E + 255) / 256, 256, 0, stream>>>(ei, E, N, flags, degcnt);
    gnn_dis<<<nbN, 256, 0, stream>>>(degcnt, dis, N);
    gnn_scan1<<<nbN, 256, 0, stream>>>(degcnt, row_ptr, sums, N);
    gnn_scan2<<<1, 256, 0, stream>>>(sums, nbN);
    gnn_scan3<<<nbN, 256, 0, stream>>>(row_ptr, sums, N, E);
    gnn_fill<<<(E + 255) / 256, 256, 0, stream>>>(ei, dis, row_ptr, fillcnt,
                                                  csr_src, csr_norm, E, N, flags);

    // 2) layer 1: A = x @ W1 ; C = relu(aggregate(A) + b1)
    gnn_linear<<<(N + 7) / 8, 256, 0, stream>>>(x, wsW + OW1, 64, N, flags, 0, A);
    gnn_aggregate<<<N, 128, 0, stream>>>(A, row_ptr, csr_src, csr_norm, dis, wsW + OB1, C, N);

    // 3) layer 2: A = C @ W2 ; C = relu(aggregate(A) + b2)
    gnn_linear<<<(N + 7) / 8, 256, 0, stream>>>((const void*)C, wsW + OW2, 128, N, flags, 1, A);
    gnn_aggregate<<<N, 128, 0, stream>>>(A, row_ptr, csr_src, csr_norm, dis, wsW + OB2, C, N);

    // 4) pool + head
    gnn_pool<<<(N + 127) / 128, 128, 0, stream>>>(C, bat, flags, pooled, cntf, N, B);
    gnn_head1<<<B, 128, 0, stream>>>(pooled, cntf, wsW + OW3, wsW + OB3, r);
    gnn_head2<<<B, 64, 0, stream>>>(r, wsW + OW4, wsW + OB4, flags, d_out);
}

// Round 3
// 437.938 us; speedup vs baseline: 1.1970x; 1.1970x over previous
//
#include <hip/hip_runtime.h>

// ---------------- dtype-adaptive accessors ----------------

__device__ __forceinline__ float ldf(const void* p, long long i, int f32) {
    if (f32) return ((const float*)p)[i];
    unsigned int u = ((const unsigned short*)p)[i];
    return __uint_as_float(u << 16);
}
__device__ __forceinline__ float bf2f(unsigned short u) {
    return __uint_as_float(((unsigned int)u) << 16);
}
__device__ __forceinline__ int ld_idx(const int* p, long long i, int i64) {
    return i64 ? p[2 * i] : p[i];   // little-endian low word of int64
}
__device__ __forceinline__ unsigned short f2bf(float v) {
    unsigned int x = __float_as_uint(v);
    return (unsigned short)((x + 0x7FFFu + ((x >> 16) & 1u)) >> 16);  // RNE
}
__device__ __forceinline__ int clampi(int v, int lo, int hi) {
    return v < lo ? lo : (v > hi ? hi : v);
}

// ---------------- dtype detection ----------------
// flags[0] = 1 if float tensors are f32, 0 if bf16
// flags[1] = 1 if int tensors are int64, 0 if int32

__global__ void gnn_detect(const unsigned int* __restrict__ w1_words,
                           const int* __restrict__ ei_words,
                           int* __restrict__ flags) {
    __shared__ int cnt;
    __shared__ int orred;
    int t = threadIdx.x;
    if (t == 0) { cnt = 0; orred = 0; }
    __syncthreads();
    int c = 0, o = 0;
    for (int i = t; i < 512; i += 256) {
        unsigned int e = (w1_words[i] >> 7) & 0xFFu;   // bf16-packed: low elem's exponent
        if (e >= 100 && e <= 140) c++;
    }
    for (int i = t; i < 4096; i += 256) o |= ei_words[2 * i + 1];  // int64: high words all 0
    atomicAdd(&cnt, c);
    atomicOr(&orred, o);
    __syncthreads();
    if (t == 0) {
        flags[0] = (cnt > 256) ? 0 : 1;
        flags[1] = (orred == 0) ? 1 : 0;
    }
}

// ---------------- utilities ----------------

__global__ void gnn_zero(unsigned int* __restrict__ p, int n) {
    int i = blockIdx.x * blockDim.x + threadIdx.x;
    if (i < n) p[i] = 0u;
}

// weights -> one contiguous f32 region
#define OW1 0
#define OB1 8192
#define OW2 8320
#define OB2 24704
#define OW3 24832
#define OB3 41216
#define OW4 41344
#define OB4 49536
#define OTOT 49600

__global__ void gnn_convert_w(const void* W1, const void* b1, const void* W2, const void* b2,
                              const void* W3, const void* b3, const void* W4, const void* b4,
                              const int* __restrict__ flags, float* __restrict__ dst) {
    int f32 = flags[0];
    int i = blockIdx.x * blockDim.x + threadIdx.x;
    if (i >= OTOT) return;
    float v;
    if      (i < OB1) v = ldf(W1, i - OW1, f32);
    else if (i < OW2) v = ldf(b1, i - OB1, f32);
    else if (i < OB2) v = ldf(W2, i - OW2, f32);
    else if (i < OW3) v = ldf(b2, i - OB2, f32);
    else if (i < OB3) v = ldf(W3, i - OW3, f32);
    else if (i < OW4) v = ldf(b3, i - OB3, f32);
    else if (i < OB4) v = ldf(W4, i - OW4, f32);
    else              v = ldf(b4, i - OB4, f32);
    dst[i] = v;
}

// ---------------- CSR build ----------------

__global__ void gnn_hist(const int* __restrict__ ei, int E, int N,
                         const int* __restrict__ flags, int* __restrict__ degcnt) {
    int e = blockIdx.x * blockDim.x + threadIdx.x;
    if (e >= E) return;
    int i64 = flags[1];
    int d = clampi(ld_idx(ei, (long long)E + e, i64), 0, N - 1);
    atomicAdd(&degcnt[d], 1);
}

__global__ void gnn_dis(const int* __restrict__ degcnt, float* __restrict__ dis, int N) {
    int i = blockIdx.x * blockDim.x + threadIdx.x;
    if (i < N) dis[i] = rsqrtf((float)degcnt[i] + 1.0f);  // +1 self-loop
}

__global__ void gnn_scan1(const int* __restrict__ cnt, int* __restrict__ excl,
                          int* __restrict__ sums, int N) {
    __shared__ int sh[256];
    int t = threadIdx.x;
    int i = blockIdx.x * 256 + t;
    int v = (i < N) ? cnt[i] : 0;
    sh[t] = v;
    __syncthreads();
    for (int off = 1; off < 256; off <<= 1) {
        int a = (t >= off) ? sh[t - off] : 0;
        __syncthreads();
        sh[t] += a;
        __syncthreads();
    }
    if (i < N) excl[i] = sh[t] - v;
    if (t == 255) sums[blockIdx.x] = sh[255];
}

__global__ void gnn_scan2(int* __restrict__ sums, int nb) {
    __shared__ int sh[256];
    int t = threadIdx.x;
    int v = (t < nb) ? sums[t] : 0;
    sh[t] = v;
    __syncthreads();
    for (int off = 1; off < 256; off <<= 1) {
        int a = (t >= off) ? sh[t - off] : 0;
        __syncthreads();
        sh[t] += a;
        __syncthreads();
    }
    if (t < nb) sums[t] = sh[t] - v;
}

__global__ void gnn_scan3(int* __restrict__ row_ptr, const int* __restrict__ sums,
                          int N, int E) {
    int i = blockIdx.x * 256 + threadIdx.x;
    if (i < N) row_ptr[i] += sums[blockIdx.x];
    if (i == 0) row_ptr[N] = E;
}

__global__ void gnn_fill(const int* __restrict__ ei, const float* __restrict__ dis,
                         const int* __restrict__ row_ptr, int* __restrict__ fillcnt,
                         int* __restrict__ csr_src, float* __restrict__ csr_norm,
                         int E, int N, const int* __restrict__ flags) {
    int e = blockIdx.x * blockDim.x + threadIdx.x;
    if (e >= E) return;
    int i64 = flags[1];
    int s = clampi(ld_idx(ei, (long long)e, i64), 0, N - 1);
    int d = clampi(ld_idx(ei, (long long)E + e, i64), 0, N - 1);
    int pos = row_ptr[d] + atomicAdd(&fillcnt[d], 1);
    csr_src[pos] = s;
    csr_norm[pos] = dis[s] * dis[d];
}

// ---------------- Layer-1 aggregation on raw x (64-dim, dtype-flagged) ----------------
// aggX[n,f] = sum_e norm*x[src,f] + dis[n]^2 * x[n,f];  4 nodes/block (wave per node)

__global__ __launch_bounds__(256) void gnn_agg_x(const void* __restrict__ x,
                                                 const int* __restrict__ rp,
                                                 const int* __restrict__ cs,
                                                 const float* __restrict__ cn,
                                                 const float* __restrict__ dis,
                                                 const int* __restrict__ flags,
                                                 float* __restrict__ aggX, int N) {
    int t = threadIdx.x;
    int n = blockIdx.x * 4 + (t >> 6);
    if (n >= N) return;
    int f = t & 63;
    int xf32 = flags[0];
    float dn = dis[n];
    float acc = ldf(x, (long long)n * 64 + f, xf32) * (dn * dn);
    int beg = rp[n], end = rp[n + 1];
    for (int e = beg; e < end; ++e) {
        int s = cs[e];                 // wave-uniform
        float w = cn[e];
        acc += w * ldf(x, (long long)s * 64 + f, xf32);
    }
    aggX[(long long)n * 64 + f] = acc;
}

// ---------------- Linear: out[N,128] = X[N,K] @ W[K,128]  (32 nodes/block) -------------
// thread tile: 4 features x 4 nodes; per k: 1 ds_read_b128 (W) + 4 broadcast b32 (X), 16 FMA

template <int K, bool RELU, bool OUTBF>
__global__ __launch_bounds__(256) void gnn_linear(const float* __restrict__ X,
                                                  const float* __restrict__ Wf,
                                                  const float* __restrict__ bias,
                                                  int N, void* __restrict__ out) {
    __shared__ float Wl[64 * 128];     // 32 KB
    __shared__ float Xs[32 * K];       // 8/16 KB
    const int t = threadIdx.x;
    const int nbase = blockIdx.x * 32;

    // stage X tile (float4)
#pragma unroll
    for (int it = 0; it < K / 32; ++it) {
        int i4 = t + it * 256;                   // float4 index within tile
        int n = nbase + (i4 * 4) / K;
        float4 v = make_float4(0.f, 0.f, 0.f, 0.f);
        if (n < N) v = ((const float4*)X)[(long long)nbase * (K / 4) + i4];
        ((float4*)Xs)[i4] = v;
    }

    const int fg = t & 31, ng = t >> 5;
    const int f0 = fg * 4, n0 = ng * 4;
    float4 acc[4];
#pragma unroll
    for (int j = 0; j < 4; ++j) acc[j] = make_float4(0.f, 0.f, 0.f, 0.f);

    for (int kc = 0; kc < K; kc += 64) {
        __syncthreads();
#pragma unroll
        for (int it = 0; it < 8; ++it) {
            int i4 = t + it * 256;
            ((float4*)Wl)[i4] = ((const float4*)(Wf + kc * 128))[i4];
        }
        __syncthreads();
#pragma unroll 4
        for (int k = 0; k < 64; ++k) {
            const float4 w = *(const float4*)&Wl[k * 128 + f0];
#pragma unroll
            for (int j = 0; j < 4; ++j) {
                float xv = Xs[(n0 + j) * K + kc + k];
                acc[j].x = fmaf(xv, w.x, acc[j].x);
                acc[j].y = fmaf(xv, w.y, acc[j].y);
                acc[j].z = fmaf(xv, w.z, acc[j].z);
                acc[j].w = fmaf(xv, w.w, acc[j].w);
            }
        }
    }

#pragma unroll
    for (int j = 0; j < 4; ++j) {
        int n = nbase + n0 + j;
        if (n >= N) continue;
        float4 a = acc[j];
        if (RELU) {
            const float4 b = *(const float4*)&bias[f0];
            a.x = fmaxf(a.x + b.x, 0.f);
            a.y = fmaxf(a.y + b.y, 0.f);
            a.z = fmaxf(a.z + b.z, 0.f);
            a.w = fmaxf(a.w + b.w, 0.f);
        }
        if (OUTBF) {
            uint2 u;
            u.x = (unsigned int)f2bf(a.x) | ((unsigned int)f2bf(a.y) << 16);
            u.y = (unsigned int)f2bf(a.z) | ((unsigned int)f2bf(a.w) << 16);
            *(uint2*)((unsigned short*)out + (long long)n * 128 + f0) = u;
        } else {
            *(float4*)((float*)out + (long long)n * 128 + f0) = a;
        }
    }
}

// ---------------- Layer-2 aggregation over bf16 rows (128-dim) -------------------------
// 4 nodes/block (wave per node); thread handles feature pair via uint load

__global__ __launch_bounds__(256) void gnn_agg_bf(const unsigned short* __restrict__ A2,
                                                  const int* __restrict__ rp,
                                                  const int* __restrict__ cs,
                                                  const float* __restrict__ cn,
                                                  const float* __restrict__ dis,
                                                  const float* __restrict__ bias,
                                                  float* __restrict__ outC, int N) {
    int t = threadIdx.x;
    int n = blockIdx.x * 4 + (t >> 6);
    if (n >= N) return;
    int f2 = t & 63;                    // features 2*f2, 2*f2+1
    float dn = dis[n];
    float dn2 = dn * dn;
    unsigned int su = *(const unsigned int*)(A2 + (long long)n * 128 + 2 * f2);
    float accx = bf2f((unsigned short)(su & 0xFFFFu)) * dn2;
    float accy = bf2f((unsigned short)(su >> 16)) * dn2;
    int beg = rp[n], end = rp[n + 1];
    for (int e = beg; e < end; ++e) {
        int s = cs[e];                  // wave-uniform
        float w = cn[e];
        unsigned int u = *(const unsigned int*)(A2 + (long long)s * 128 + 2 * f2);
        accx = fmaf(w, bf2f((unsigned short)(u & 0xFFFFu)), accx);
        accy = fmaf(w, bf2f((unsigned short)(u >> 16)), accy);
    }
    accx += bias[2 * f2];
    accy += bias[2 * f2 + 1];
    float2 o;
    o.x = fmaxf(accx, 0.f);
    o.y = fmaxf(accy, 0.f);
    *(float2*)(outC + (long long)n * 128 + 2 * f2) = o;
}

// ---------------- Pool (batch sorted) ----------------

__global__ __launch_bounds__(128) void gnn_pool(const float* __restrict__ h,
                                                const int* __restrict__ batch,
                                                const int* __restrict__ flags,
                                                float* __restrict__ pooled,
                                                float* __restrict__ cntf, int N, int B) {
    int i64 = flags[1];
    int f = threadIdx.x;
    int n0 = blockIdx.x * 128;
    if (n0 >= N) return;
    int nend = min(n0 + 128, N);
    int cur = clampi(ld_idx(batch, n0, i64), 0, B - 1);
    float acc = 0.0f;
    int cc = 0;
    for (int n = n0; n < nend; ++n) {
        int b = clampi(ld_idx(batch, n, i64), 0, B - 1);
        if (b != cur) {
            atomicAdd(&pooled[cur * 128 + f], acc);
            if (f == 0) atomicAdd(&cntf[cur], (float)cc);
            acc = 0.0f; cc = 0; cur = b;
        }
        acc += h[(long long)n * 128 + f];
        ++cc;
    }
    atomicAdd(&pooled[cur * 128 + f], acc);
    if (f == 0) atomicAdd(&cntf[cur], (float)cc);
}

// ---------------- Head ----------------

__global__ __launch_bounds__(128) void gnn_head1(const float* __restrict__ pooled,
                                                 const float* __restrict__ cntf,
                                                 const float* __restrict__ W3,
                                                 const float* __restrict__ b3,
                                                 float* __restrict__ r) {
    __shared__ float xs[128];
    int b = blockIdx.x, f = threadIdx.x;
    float c = fmaxf(cntf[b], 1.0f);
    xs[f] = pooled[b * 128 + f] / c;
    __syncthreads();
    float acc = b3[f];
    for (int k = 0; k < 128; ++k) acc += xs[k] * W3[k * 128 + f];
    r[b * 128 + f] = fmaxf(acc, 0.0f);
}

__global__ __launch_bounds__(64) void gnn_head2(const float* __restrict__ r,
                                                const float* __restrict__ W4,
                                                const float* __restrict__ b4,
                                                const int* __restrict__ flags,
                                                void* __restrict__ outv) {
    __shared__ float xs[128];
    int b = blockIdx.x, f = threadIdx.x;
    xs[f] = r[b * 128 + f];
    xs[f + 64] = r[b * 128 + f + 64];
    __syncthreads();
    float acc = b4[f];
    for (int k = 0; k < 128; ++k) acc += xs[k] * W4[k * 64 + f];
    if (flags[0]) ((float*)outv)[b * 64 + f] = acc;
    else          ((unsigned short*)outv)[b * 64 + f] = f2bf(acc);
}

// ---------------- Launch ----------------

extern "C" void kernel_launch(void* const* d_in, const int* in_sizes, int n_in,
                              void* d_out, int out_size, void* d_ws, size_t ws_size,
                              hipStream_t stream) {
    const void* x  = d_in[0];
    const int* ei  = (const int*)d_in[1];
    const int* bat = (const int*)d_in[2];

    const int N = in_sizes[0] / 64;    // 50000
    const int E = in_sizes[1] / 2;     // 800000
    const int B = out_size / 64;       // 64

    char* p = (char*)d_ws;
    auto alloc = [&](size_t bytes) { void* q = (void*)p; p += (bytes + 255) & ~(size_t)255; return q; };
    int*   flags    = (int*)alloc(256);
    float* wsW      = (float*)alloc((size_t)OTOT * 4);
    int*   degcnt   = (int*)alloc((size_t)N * 4);
    int*   fillcnt  = (int*)alloc((size_t)N * 4);
    float* dis      = (float*)alloc((size_t)N * 4);
    int*   row_ptr  = (int*)alloc((size_t)(N + 1) * 4);
    int*   sums     = (int*)alloc(1024);
    int*   csr_src  = (int*)alloc((size_t)E * 4);
    float* csr_norm = (float*)alloc((size_t)E * 4);
    float* R1       = (float*)alloc((size_t)N * 128 * 4);   // aggX (N x 64), later C2 (N x 128)
    float* R2       = (float*)alloc((size_t)N * 128 * 4);   // C = layer-1 output (N x 128)
    unsigned short* R3 = (unsigned short*)alloc((size_t)N * 128 * 2);  // A2 bf16
    float* pooled   = (float*)alloc((size_t)B * 128 * 4);
    float* cntf     = (float*)alloc((size_t)B * 4);
    float* r        = (float*)alloc((size_t)B * 128 * 4);
    (void)ws_size; (void)n_in;

    const int nbN = (N + 255) / 256;   // 196 (fits single-block scan2)

    // 0) detection + zero-init + weight conversion
    gnn_detect<<<1, 256, 0, stream>>>((const unsigned int*)d_in[3], ei, flags);
    gnn_zero<<<nbN, 256, 0, stream>>>((unsigned int*)degcnt, N);
    gnn_zero<<<nbN, 256, 0, stream>>>((unsigned int*)fillcnt, N);
    gnn_zero<<<(B * 128 + 255) / 256, 256, 0, stream>>>((unsigned int*)pooled, B * 128);
    gnn_zero<<<1, 256, 0, stream>>>((unsigned int*)cntf, B);
    gnn_convert_w<<<(OTOT + 255) / 256, 256, 0, stream>>>(d_in[3], d_in[4], d_in[5], d_in[6],
                                                          d_in[7], d_in[8], d_in[9], d_in[10],
                                                          flags, wsW);

    // 1) CSR build
    gnn_hist<<<(E + 255) / 256, 256, 0, stream>>>(ei, E, N, flags, degcnt);
    gnn_dis<<<nbN, 256, 0, stream>>>(degcnt, dis, N);
    gnn_scan1<<<nbN, 256, 0, stream>>>(degcnt, row_ptr, sums, N);
    gnn_scan2<<<1, 256, 0, stream>>>(sums, nbN);
    gnn_scan3<<<nbN, 256, 0, stream>>>(row_ptr, sums, N, E);
    gnn_fill<<<(E + 255) / 256, 256, 0, stream>>>(ei, dis, row_ptr, fillcnt,
                                                  csr_src, csr_norm, E, N, flags);

    const int nlin = (N + 31) / 32;

    // 2) layer 1: aggX = A_hat @ x ; C = relu(aggX @ W1 + b1)
    gnn_agg_x<<<(N + 3) / 4, 256, 0, stream>>>(x, row_ptr, csr_src, csr_norm, dis, flags, R1, N);
    gnn_linear<64, true, false><<<nlin, 256, 0, stream>>>(R1, wsW + OW1, wsW + OB1, N, (void*)R2);

    // 3) layer 2: A2 = C @ W2 (bf16) ; C2 = relu(A_hat @ A2 + b2)
    gnn_linear<128, false, true><<<nlin, 256, 0, stream>>>(R2, wsW + OW2, wsW + OB2, N, (void*)R3);
    gnn_agg_bf<<<(N + 3) / 4, 256, 0, stream>>>(R3, row_ptr, csr_src, csr_norm, dis,
                                                wsW + OB2, R1, N);

    // 4) pool + head
    gnn_pool<<<(N + 127) / 128, 128, 0, stream>>>(R1, bat, flags, pooled, cntf, N, B);
    gnn_head1<<<B, 128, 0, stream>>>(pooled, cntf, wsW + OW3, wsW + OB3, r);
    gnn_head2<<<B, 64, 0, stream>>>(r, wsW + OW4, wsW + OB4, flags, d_out);
}

// Round 4
// 330.613 us; speedup vs baseline: 1.5856x; 1.3246x over previous
//
#include <hip/hip_runtime.h>

// ---------------- helpers ----------------

__device__ __forceinline__ float ldf(const void* p, long long i, int f32) {
    if (f32) return ((const float*)p)[i];
    unsigned int u = ((const unsigned short*)p)[i];
    return __uint_as_float(u << 16);
}
__device__ __forceinline__ float bfl(unsigned int u) { return __uint_as_float(u << 16); }
__device__ __forceinline__ float bfh(unsigned int u) { return __uint_as_float(u & 0xFFFF0000u); }
__device__ __forceinline__ int ld_idx(const int* p, long long i, int i64) {
    return i64 ? p[2 * i] : p[i];   // little-endian low word of int64
}
__device__ __forceinline__ unsigned short f2bf(float v) {
    unsigned int x = __float_as_uint(v);
    return (unsigned short)((x + 0x7FFFu + ((x >> 16) & 1u)) >> 16);  // RNE
}
__device__ __forceinline__ int clampi(int v, int lo, int hi) {
    return v < lo ? lo : (v > hi ? hi : v);
}

// ---------------- dtype detection ----------------
// flags[0]=1 f32 floats / 0 bf16 ; flags[1]=1 int64 / 0 int32

__global__ void gnn_detect(const unsigned int* __restrict__ w1_words,
                           const int* __restrict__ ei_words,
                           int* __restrict__ flags) {
    __shared__ int cnt;
    __shared__ int orred;
    int t = threadIdx.x;
    if (t == 0) { cnt = 0; orred = 0; }
    __syncthreads();
    int c = 0, o = 0;
    for (int i = t; i < 512; i += 256) {
        unsigned int e = (w1_words[i] >> 7) & 0xFFu;
        if (e >= 100 && e <= 140) c++;
    }
    for (int i = t; i < 4096; i += 256) o |= ei_words[2 * i + 1];
    atomicAdd(&cnt, c);
    atomicOr(&orred, o);
    __syncthreads();
    if (t == 0) {
        flags[0] = (cnt > 256) ? 0 : 1;
        flags[1] = (orred == 0) ? 1 : 0;
    }
}

// ---------------- fused zero-init ----------------

__global__ void gnn_zeroall(int* __restrict__ degcnt, int* __restrict__ fillcnt,
                            float* __restrict__ pooled, float* __restrict__ cntf,
                            int N, int B) {
    int i = blockIdx.x * 256 + threadIdx.x;
    int stride = gridDim.x * 256;
    for (int j = i; j < N; j += stride) { degcnt[j] = 0; fillcnt[j] = 0; }
    for (int j = i; j < B * 128; j += stride) pooled[j] = 0.f;
    for (int j = i; j < B; j += stride) cntf[j] = 0.f;
}

// ---------------- weights -> contiguous f32 ----------------
#define OW1 0
#define OB1 8192
#define OW2 8320
#define OB2 24704
#define OW3 24832
#define OB3 41216
#define OW4 41344
#define OB4 49536
#define OTOT 49600

__global__ void gnn_convert_w(const void* W1, const void* b1, const void* W2, const void* b2,
                              const void* W3, const void* b3, const void* W4, const void* b4,
                              const int* __restrict__ flags, float* __restrict__ dst) {
    int f32 = flags[0];
    int i = blockIdx.x * blockDim.x + threadIdx.x;
    if (i >= OTOT) return;
    float v;
    if      (i < OB1) v = ldf(W1, i - OW1, f32);
    else if (i < OW2) v = ldf(b1, i - OB1, f32);
    else if (i < OB2) v = ldf(W2, i - OW2, f32);
    else if (i < OW3) v = ldf(b2, i - OB2, f32);
    else if (i < OB3) v = ldf(W3, i - OW3, f32);
    else if (i < OW4) v = ldf(b3, i - OB3, f32);
    else if (i < OB4) v = ldf(W4, i - OW4, f32);
    else              v = ldf(b4, i - OB4, f32);
    dst[i] = v;
}

// x -> bf16 (only needed when x is f32; bf16 path uses input directly)
__global__ void gnn_convert_x(const void* __restrict__ x, const int* __restrict__ flags,
                              unsigned short* __restrict__ xb, int n64) {
    if (!flags[0]) return;
    int i = blockIdx.x * 256 + threadIdx.x;
    if (i < n64) xb[i] = f2bf(((const float*)x)[i]);
}

// ---------------- CSR build ----------------

__global__ void gnn_hist(const int* __restrict__ ei, int E, int N,
                         const int* __restrict__ flags, int* __restrict__ degcnt) {
    int e = blockIdx.x * blockDim.x + threadIdx.x;
    if (e >= E) return;
    int i64 = flags[1];
    int d = clampi(ld_idx(ei, (long long)E + e, i64), 0, N - 1);
    atomicAdd(&degcnt[d], 1);
}

// scan1 also produces dis = rsqrt(deg+1)
__global__ void gnn_scan1(const int* __restrict__ cnt, int* __restrict__ excl,
                          int* __restrict__ sums, float* __restrict__ dis, int N) {
    __shared__ int sh[256];
    int t = threadIdx.x;
    int i = blockIdx.x * 256 + t;
    int v = (i < N) ? cnt[i] : 0;
    sh[t] = v;
    __syncthreads();
    for (int off = 1; off < 256; off <<= 1) {
        int a = (t >= off) ? sh[t - off] : 0;
        __syncthreads();
        sh[t] += a;
        __syncthreads();
    }
    if (i < N) {
        excl[i] = sh[t] - v;
        dis[i] = rsqrtf((float)v + 1.0f);
    }
    if (t == 255) sums[blockIdx.x] = sh[255];
}

__global__ void gnn_scan2(int* __restrict__ sums, int nb) {
    __shared__ int sh[256];
    int t = threadIdx.x;
    int v = (t < nb) ? sums[t] : 0;
    sh[t] = v;
    __syncthreads();
    for (int off = 1; off < 256; off <<= 1) {
        int a = (t >= off) ? sh[t - off] : 0;
        __syncthreads();
        sh[t] += a;
        __syncthreads();
    }
    if (t < nb) sums[t] = sh[t] - v;
}

__global__ void gnn_scan3(int* __restrict__ row_ptr, const int* __restrict__ sums,
                          int N, int E) {
    int i = blockIdx.x * 256 + threadIdx.x;
    if (i < N) row_ptr[i] += sums[blockIdx.x];
    if (i == 0) row_ptr[N] = E;
}

// csr entry = {src, norm_bits} packed int2
__global__ void gnn_fill(const int* __restrict__ ei, const float* __restrict__ dis,
                         const int* __restrict__ row_ptr, int* __restrict__ fillcnt,
                         int2* __restrict__ csr, int E, int N, const int* __restrict__ flags) {
    int e = blockIdx.x * blockDim.x + threadIdx.x;
    if (e >= E) return;
    int i64 = flags[1];
    int s = clampi(ld_idx(ei, (long long)e, i64), 0, N - 1);
    int d = clampi(ld_idx(ei, (long long)E + e, i64), 0, N - 1);
    int pos = row_ptr[d] + atomicAdd(&fillcnt[d], 1);
    csr[pos] = make_int2(s, __float_as_int(dis[s] * dis[d]));
}

// ---------------- Layer-1 aggregation on bf16 x (64 feats) ----------------
// 2 nodes/wave (half-wave per node), lane covers 2 feats via uint; 4-wide edge unroll.

__global__ __launch_bounds__(256) void gnn_agg_x(const void* __restrict__ x,
                                                 const unsigned short* __restrict__ xconv,
                                                 const int* __restrict__ rp,
                                                 const int2* __restrict__ csr,
                                                 const float* __restrict__ dis,
                                                 const int* __restrict__ flags,
                                                 float* __restrict__ aggX, int N) {
    const unsigned int* tab = flags[0] ? (const unsigned int*)xconv : (const unsigned int*)x;
    int t = threadIdx.x;
    int lane = t & 63;
    int n = blockIdx.x * 8 + (t >> 6) * 2 + (lane >> 5);
    if (n >= N) return;
    int fl = lane & 31;                          // uint index within 32-uint row
    float dn = dis[n];
    float dn2 = dn * dn;
    unsigned int us = tab[(long long)n * 32 + fl];
    float a0 = bfl(us) * dn2, a1 = bfh(us) * dn2;
    int beg = rp[n], end = rp[n + 1];
    int e = beg;
    for (; e + 4 <= end; e += 4) {
        int2 c0 = csr[e], c1 = csr[e + 1], c2 = csr[e + 2], c3 = csr[e + 3];
        unsigned int u0 = tab[(long long)c0.x * 32 + fl];
        unsigned int u1 = tab[(long long)c1.x * 32 + fl];
        unsigned int u2 = tab[(long long)c2.x * 32 + fl];
        unsigned int u3 = tab[(long long)c3.x * 32 + fl];
        float w0 = __int_as_float(c0.y), w1 = __int_as_float(c1.y);
        float w2 = __int_as_float(c2.y), w3 = __int_as_float(c3.y);
        a0 = fmaf(w0, bfl(u0), a0); a1 = fmaf(w0, bfh(u0), a1);
        a0 = fmaf(w1, bfl(u1), a0); a1 = fmaf(w1, bfh(u1), a1);
        a0 = fmaf(w2, bfl(u2), a0); a1 = fmaf(w2, bfh(u2), a1);
        a0 = fmaf(w3, bfl(u3), a0); a1 = fmaf(w3, bfh(u3), a1);
    }
    for (; e < end; ++e) {
        int2 c = csr[e];
        unsigned int u = tab[(long long)c.x * 32 + fl];
        float w = __int_as_float(c.y);
        a0 = fmaf(w, bfl(u), a0); a1 = fmaf(w, bfh(u), a1);
    }
    *(float2*)(aggX + (long long)n * 64 + fl * 2) = make_float2(a0, a1);
}

// ---------------- Linear: out[N,128] = X[N,K] @ W[K,128]  (32 nodes/block) -------------

template <int K, bool RELU, bool OUTBF>
__global__ __launch_bounds__(256) void gnn_linear(const float* __restrict__ X,
                                                  const float* __restrict__ Wf,
                                                  const float* __restrict__ bias,
                                                  int N, void* __restrict__ out) {
    __shared__ float Wl[64 * 128];
    __shared__ float Xs[32 * K];
    const int t = threadIdx.x;
    const int nbase = blockIdx.x * 32;

#pragma unroll
    for (int it = 0; it < K / 32; ++it) {
        int i4 = t + it * 256;
        int n = nbase + (i4 * 4) / K;
        float4 v = make_float4(0.f, 0.f, 0.f, 0.f);
        if (n < N) v = ((const float4*)X)[(long long)nbase * (K / 4) + i4];
        ((float4*)Xs)[i4] = v;
    }

    const int fg = t & 31, ng = t >> 5;
    const int f0 = fg * 4, n0 = ng * 4;
    float4 acc[4];
#pragma unroll
    for (int j = 0; j < 4; ++j) acc[j] = make_float4(0.f, 0.f, 0.f, 0.f);

    for (int kc = 0; kc < K; kc += 64) {
        __syncthreads();
#pragma unroll
        for (int it = 0; it < 8; ++it) {
            int i4 = t + it * 256;
            ((float4*)Wl)[i4] = ((const float4*)(Wf + kc * 128))[i4];
        }
        __syncthreads();
#pragma unroll 4
        for (int k = 0; k < 64; ++k) {
            const float4 w = *(const float4*)&Wl[k * 128 + f0];
#pragma unroll
            for (int j = 0; j < 4; ++j) {
                float xv = Xs[(n0 + j) * K + kc + k];
                acc[j].x = fmaf(xv, w.x, acc[j].x);
                acc[j].y = fmaf(xv, w.y, acc[j].y);
                acc[j].z = fmaf(xv, w.z, acc[j].z);
                acc[j].w = fmaf(xv, w.w, acc[j].w);
            }
        }
    }

#pragma unroll
    for (int j = 0; j < 4; ++j) {
        int n = nbase + n0 + j;
        if (n >= N) continue;
        float4 a = acc[j];
        if (RELU) {
            const float4 b = *(const float4*)&bias[f0];
            a.x = fmaxf(a.x + b.x, 0.f);
            a.y = fmaxf(a.y + b.y, 0.f);
            a.z = fmaxf(a.z + b.z, 0.f);
            a.w = fmaxf(a.w + b.w, 0.f);
        }
        if (OUTBF) {
            uint2 u;
            u.x = (unsigned int)f2bf(a.x) | ((unsigned int)f2bf(a.y) << 16);
            u.y = (unsigned int)f2bf(a.z) | ((unsigned int)f2bf(a.w) << 16);
            *(uint2*)((unsigned short*)out + (long long)n * 128 + f0) = u;
        } else {
            *(float4*)((float*)out + (long long)n * 128 + f0) = a;
        }
    }
}

// ---------------- Layer-2 aggregation over bf16 rows (128 feats) ----------------
// 2 nodes/wave, lane covers 4 feats via uint2; 4-wide edge unroll.

__global__ __launch_bounds__(256) void gnn_agg_bf(const unsigned short* __restrict__ A2,
                                                  const int* __restrict__ rp,
                                                  const int2* __restrict__ csr,
                                                  const float* __restrict__ dis,
                                                  const float* __restrict__ bias,
                                                  float* __restrict__ outC, int N) {
    int t = threadIdx.x;
    int lane = t & 63;
    int n = blockIdx.x * 8 + (t >> 6) * 2 + (lane >> 5);
    if (n >= N) return;
    int fl = lane & 31;                          // uint2 index within row
    float dn = dis[n];
    float dn2 = dn * dn;
    uint2 us = *(const uint2*)(A2 + (long long)n * 128 + fl * 4);
    float a0 = bfl(us.x) * dn2, a1 = bfh(us.x) * dn2;
    float a2 = bfl(us.y) * dn2, a3 = bfh(us.y) * dn2;
    int beg = rp[n], end = rp[n + 1];
    int e = beg;
    for (; e + 4 <= end; e += 4) {
        int2 c0 = csr[e], c1 = csr[e + 1], c2 = csr[e + 2], c3 = csr[e + 3];
        uint2 u0 = *(const uint2*)(A2 + (long long)c0.x * 128 + fl * 4);
        uint2 u1 = *(const uint2*)(A2 + (long long)c1.x * 128 + fl * 4);
        uint2 u2 = *(const uint2*)(A2 + (long long)c2.x * 128 + fl * 4);
        uint2 u3 = *(const uint2*)(A2 + (long long)c3.x * 128 + fl * 4);
        float w0 = __int_as_float(c0.y), w1 = __int_as_float(c1.y);
        float w2 = __int_as_float(c2.y), w3 = __int_as_float(c3.y);
        a0 = fmaf(w0, bfl(u0.x), a0); a1 = fmaf(w0, bfh(u0.x), a1);
        a2 = fmaf(w0, bfl(u0.y), a2); a3 = fmaf(w0, bfh(u0.y), a3);
        a0 = fmaf(w1, bfl(u1.x), a0); a1 = fmaf(w1, bfh(u1.x), a1);
        a2 = fmaf(w1, bfl(u1.y), a2); a3 = fmaf(w1, bfh(u1.y), a3);
        a0 = fmaf(w2, bfl(u2.x), a0); a1 = fmaf(w2, bfh(u2.x), a1);
        a2 = fmaf(w2, bfl(u2.y), a2); a3 = fmaf(w2, bfh(u2.y), a3);
        a0 = fmaf(w3, bfl(u3.x), a0); a1 = fmaf(w3, bfh(u3.x), a1);
        a2 = fmaf(w3, bfl(u3.y), a2); a3 = fmaf(w3, bfh(u3.y), a3);
    }
    for (; e < end; ++e) {
        int2 c = csr[e];
        uint2 u = *(const uint2*)(A2 + (long long)c.x * 128 + fl * 4);
        float w = __int_as_float(c.y);
        a0 = fmaf(w, bfl(u.x), a0); a1 = fmaf(w, bfh(u.x), a1);
        a2 = fmaf(w, bfl(u.y), a2); a3 = fmaf(w, bfh(u.y), a3);
    }
    const float4 b = *(const float4*)&bias[fl * 4];
    float4 o;
    o.x = fmaxf(a0 + b.x, 0.f);
    o.y = fmaxf(a1 + b.y, 0.f);
    o.z = fmaxf(a2 + b.z, 0.f);
    o.w = fmaxf(a3 + b.w, 0.f);
    *(float4*)(outC + (long long)n * 128 + fl * 4) = o;
}

// ---------------- Pool (batch sorted) ----------------

__global__ __launch_bounds__(128) void gnn_pool(const float* __restrict__ h,
                                                const int* __restrict__ batch,
                                                const int* __restrict__ flags,
                                                float* __restrict__ pooled,
                                                float* __restrict__ cntf, int N, int B) {
    int i64 = flags[1];
    int f = threadIdx.x;
    int n0 = blockIdx.x * 128;
    if (n0 >= N) return;
    int nend = min(n0 + 128, N);
    int cur = clampi(ld_idx(batch, n0, i64), 0, B - 1);
    float acc = 0.0f;
    int cc = 0;
    for (int n = n0; n < nend; ++n) {
        int b = clampi(ld_idx(batch, n, i64), 0, B - 1);
        if (b != cur) {
            atomicAdd(&pooled[cur * 128 + f], acc);
            if (f == 0) atomicAdd(&cntf[cur], (float)cc);
            acc = 0.0f; cc = 0; cur = b;
        }
        acc += h[(long long)n * 128 + f];
        ++cc;
    }
    atomicAdd(&pooled[cur * 128 + f], acc);
    if (f == 0) atomicAdd(&cntf[cur], (float)cc);
}

// ---------------- Fused head ----------------

__global__ __launch_bounds__(128) void gnn_head(const float* __restrict__ pooled,
                                                const float* __restrict__ cntf,
                                                const float* __restrict__ W3,
                                                const float* __restrict__ b3,
                                                const float* __restrict__ W4,
                                                const float* __restrict__ b4,
                                                const int* __restrict__ flags,
                                                void* __restrict__ outv) {
    __shared__ float xs[128];
    __shared__ float rs[128];
    int b = blockIdx.x, f = threadIdx.x;
    float c = fmaxf(cntf[b], 1.0f);
    xs[f] = pooled[b * 128 + f] / c;
    __syncthreads();
    float acc = b3[f];
    for (int k = 0; k < 128; ++k) acc = fmaf(xs[k], W3[k * 128 + f], acc);
    rs[f] = fmaxf(acc, 0.f);
    __syncthreads();
    if (f < 64) {
        float a2 = b4[f];
        for (int k = 0; k < 128; ++k) a2 = fmaf(rs[k], W4[k * 64 + f], a2);
        if (flags[0]) ((float*)outv)[b * 64 + f] = a2;
        else          ((unsigned short*)outv)[b * 64 + f] = f2bf(a2);
    }
}

// ---------------- Launch ----------------

extern "C" void kernel_launch(void* const* d_in, const int* in_sizes, int n_in,
                              void* d_out, int out_size, void* d_ws, size_t ws_size,
                              hipStream_t stream) {
    const void* x  = d_in[0];
    const int* ei  = (const int*)d_in[1];
    const int* bat = (const int*)d_in[2];

    const int N = in_sizes[0] / 64;    // 50000
    const int E = in_sizes[1] / 2;     // 800000
    const int B = out_size / 64;       // 64

    char* p = (char*)d_ws;
    auto alloc = [&](size_t bytes) { void* q = (void*)p; p += (bytes + 255) & ~(size_t)255; return q; };
    int*   flags    = (int*)alloc(256);
    float* wsW      = (float*)alloc((size_t)OTOT * 4);
    int*   degcnt   = (int*)alloc((size_t)N * 4);
    int*   fillcnt  = (int*)alloc((size_t)N * 4);
    float* dis      = (float*)alloc((size_t)N * 4);
    int*   row_ptr  = (int*)alloc((size_t)(N + 1) * 4);
    int*   sums     = (int*)alloc(1024);
    int2*  csr      = (int2*)alloc((size_t)E * 8);
    unsigned short* xb = (unsigned short*)alloc((size_t)N * 64 * 2);
    float* C2       = (float*)alloc((size_t)N * 128 * 4);   // aggX (Nx64) then final C2 (Nx128)
    float* H1       = (float*)alloc((size_t)N * 128 * 4);   // layer-1 output
    unsigned short* A2 = (unsigned short*)alloc((size_t)N * 128 * 2);
    float* pooled   = (float*)alloc((size_t)B * 128 * 4);
    float* cntf     = (float*)alloc((size_t)B * 4);
    (void)ws_size; (void)n_in;

    const int nbN = (N + 255) / 256;   // 196

    gnn_detect<<<1, 256, 0, stream>>>((const unsigned int*)d_in[3], ei, flags);
    gnn_zeroall<<<200, 256, 0, stream>>>(degcnt, fillcnt, pooled, cntf, N, B);
    gnn_convert_w<<<(OTOT + 255) / 256, 256, 0, stream>>>(d_in[3], d_in[4], d_in[5], d_in[6],
                                                          d_in[7], d_in[8], d_in[9], d_in[10],
                                                          flags, wsW);
    gnn_convert_x<<<(N * 64 + 255) / 256, 256, 0, stream>>>(x, flags, xb, N * 64);

    gnn_hist<<<(E + 255) / 256, 256, 0, stream>>>(ei, E, N, flags, degcnt);
    gnn_scan1<<<nbN, 256, 0, stream>>>(degcnt, row_ptr, sums, dis, N);
    gnn_scan2<<<1, 256, 0, stream>>>(sums, nbN);
    gnn_scan3<<<nbN, 256, 0, stream>>>(row_ptr, sums, N, E);
    gnn_fill<<<(E + 255) / 256, 256, 0, stream>>>(ei, dis, row_ptr, fillcnt, csr, E, N, flags);

    const int nlin = (N + 31) / 32;
    const int nagg = (N + 7) / 8;

    // layer 1: aggX = A_hat @ x ; H1 = relu(aggX @ W1 + b1)
    gnn_agg_x<<<nagg, 256, 0, stream>>>(x, xb, row_ptr, csr, dis, flags, C2, N);
    gnn_linear<64, true, false><<<nlin, 256, 0, stream>>>(C2, wsW + OW1, wsW + OB1, N, (void*)H1);

    // layer 2: A2 = H1 @ W2 (bf16) ; C2 = relu(A_hat @ A2 + b2)
    gnn_linear<128, false, true><<<nlin, 256, 0, stream>>>(H1, wsW + OW2, wsW + OB2, N, (void*)A2);
    gnn_agg_bf<<<nagg, 256, 0, stream>>>(A2, row_ptr, csr, dis, wsW + OB2, C2, N);

    // pool + head
    gnn_pool<<<(N + 127) / 128, 128, 0, stream>>>(C2, bat, flags, pooled, cntf, N, B);
    gnn_head<<<B, 128, 0, stream>>>(pooled, cntf, wsW + OW3, wsW + OB3,
                                    wsW + OW4, wsW + OB4, flags, d_out);
}

// Round 5
// 319.770 us; speedup vs baseline: 1.6393x; 1.0339x over previous
//
#include <hip/hip_runtime.h>

// ---------------- helpers ----------------

__device__ __forceinline__ float ldf(const void* p, long long i, int f32) {
    if (f32) return ((const float*)p)[i];
    unsigned int u = ((const unsigned short*)p)[i];
    return __uint_as_float(u << 16);
}
__device__ __forceinline__ float bfl(unsigned int u) { return __uint_as_float(u << 16); }
__device__ __forceinline__ float bfh(unsigned int u) { return __uint_as_float(u & 0xFFFF0000u); }
__device__ __forceinline__ int ld_idx(const int* p, long long i, int i64) {
    return i64 ? p[2 * i] : p[i];   // little-endian low word of int64
}
__device__ __forceinline__ unsigned short f2bf(float v) {
    unsigned int x = __float_as_uint(v);
    return (unsigned short)((x + 0x7FFFu + ((x >> 16) & 1u)) >> 16);  // RNE
}
__device__ __forceinline__ int clampi(int v, int lo, int hi) {
    return v < lo ? lo : (v > hi ? hi : v);
}

// ---------------- dtype detection ----------------
// flags[0]=1 f32 floats / 0 bf16 ; flags[1]=1 int64 / 0 int32

__global__ void gnn_detect(const unsigned int* __restrict__ w1_words,
                           const int* __restrict__ ei_words,
                           int* __restrict__ flags) {
    __shared__ int cnt;
    __shared__ int orred;
    int t = threadIdx.x;
    if (t == 0) { cnt = 0; orred = 0; }
    __syncthreads();
    int c = 0, o = 0;
    for (int i = t; i < 512; i += 256) {
        unsigned int e = (w1_words[i] >> 7) & 0xFFu;
        if (e >= 100 && e <= 140) c++;
    }
    for (int i = t; i < 4096; i += 256) o |= ei_words[2 * i + 1];
    atomicAdd(&cnt, c);
    atomicOr(&orred, o);
    __syncthreads();
    if (t == 0) {
        flags[0] = (cnt > 256) ? 0 : 1;
        flags[1] = (orred == 0) ? 1 : 0;
    }
}

// ---------------- fused zero-init ----------------

__global__ void gnn_zeroall(int* __restrict__ degcnt, int* __restrict__ fillcnt,
                            float* __restrict__ pooled, float* __restrict__ cntf,
                            int N, int B) {
    int i = blockIdx.x * 256 + threadIdx.x;
    int stride = gridDim.x * 256;
    for (int j = i; j < N; j += stride) { degcnt[j] = 0; fillcnt[j] = 0; }
    for (int j = i; j < B * 128; j += stride) pooled[j] = 0.f;
    for (int j = i; j < B; j += stride) cntf[j] = 0.f;
}

// ---------------- weights -> contiguous f32 ----------------
#define OW1 0
#define OB1 8192
#define OW2 8320
#define OB2 24704
#define OW3 24832
#define OB3 41216
#define OW4 41344
#define OB4 49536
#define OTOT 49600

__global__ void gnn_convert_w(const void* W1, const void* b1, const void* W2, const void* b2,
                              const void* W3, const void* b3, const void* W4, const void* b4,
                              const int* __restrict__ flags, float* __restrict__ dst) {
    int f32 = flags[0];
    int i = blockIdx.x * blockDim.x + threadIdx.x;
    if (i >= OTOT) return;
    float v;
    if      (i < OB1) v = ldf(W1, i - OW1, f32);
    else if (i < OW2) v = ldf(b1, i - OB1, f32);
    else if (i < OB2) v = ldf(W2, i - OW2, f32);
    else if (i < OW3) v = ldf(b2, i - OB2, f32);
    else if (i < OB3) v = ldf(W3, i - OW3, f32);
    else if (i < OW4) v = ldf(b3, i - OB3, f32);
    else if (i < OB4) v = ldf(W4, i - OW4, f32);
    else              v = ldf(b4, i - OB4, f32);
    dst[i] = v;
}

// x -> bf16 (only needed when x is f32; bf16 path uses input directly)
__global__ void gnn_convert_x(const void* __restrict__ x, const int* __restrict__ flags,
                              unsigned short* __restrict__ xb, int n64) {
    if (!flags[0]) return;
    int i = blockIdx.x * 256 + threadIdx.x;
    if (i < n64) xb[i] = f2bf(((const float*)x)[i]);
}

// ---------------- CSR build ----------------
// 4 edges/thread: 4 independent atomic chains in flight.

__global__ void gnn_hist(const int* __restrict__ ei, int E, int N,
                         const int* __restrict__ flags, int* __restrict__ degcnt) {
    int base = (blockIdx.x * 256 + threadIdx.x) * 4;
    if (base >= E) return;
    int i64 = flags[1];
    int m = min(4, E - base);
    int d[4];
#pragma unroll
    for (int j = 0; j < 4; ++j)
        if (j < m) d[j] = clampi(ld_idx(ei, (long long)E + base + j, i64), 0, N - 1);
#pragma unroll
    for (int j = 0; j < 4; ++j)
        if (j < m) atomicAdd(&degcnt[d[j]], 1);
}

// scan1 also produces dis = rsqrt(deg+1)
__global__ void gnn_scan1(const int* __restrict__ cnt, int* __restrict__ excl,
                          int* __restrict__ sums, float* __restrict__ dis, int N) {
    __shared__ int sh[256];
    int t = threadIdx.x;
    int i = blockIdx.x * 256 + t;
    int v = (i < N) ? cnt[i] : 0;
    sh[t] = v;
    __syncthreads();
    for (int off = 1; off < 256; off <<= 1) {
        int a = (t >= off) ? sh[t - off] : 0;
        __syncthreads();
        sh[t] += a;
        __syncthreads();
    }
    if (i < N) {
        excl[i] = sh[t] - v;
        dis[i] = rsqrtf((float)v + 1.0f);
    }
    if (t == 255) sums[blockIdx.x] = sh[255];
}

__global__ void gnn_scan2(int* __restrict__ sums, int nb) {
    __shared__ int sh[256];
    int t = threadIdx.x;
    int v = (t < nb) ? sums[t] : 0;
    sh[t] = v;
    __syncthreads();
    for (int off = 1; off < 256; off <<= 1) {
        int a = (t >= off) ? sh[t - off] : 0;
        __syncthreads();
        sh[t] += a;
        __syncthreads();
    }
    if (t < nb) sums[t] = sh[t] - v;
}

__global__ void gnn_scan3(int* __restrict__ row_ptr, const int* __restrict__ sums,
                          int N, int E) {
    int i = blockIdx.x * 256 + threadIdx.x;
    if (i < N) row_ptr[i] += sums[blockIdx.x];
    if (i == 0) row_ptr[N] = E;
}

// csr entry = {src, norm_bits} packed int2; 4 edges/thread
__global__ void gnn_fill(const int* __restrict__ ei, const float* __restrict__ dis,
                         const int* __restrict__ row_ptr, int* __restrict__ fillcnt,
                         int2* __restrict__ csr, int E, int N, const int* __restrict__ flags) {
    int base = (blockIdx.x * 256 + threadIdx.x) * 4;
    if (base >= E) return;
    int i64 = flags[1];
    int m = min(4, E - base);
    int s[4], d[4];
    float ws[4], wd[4];
    int pos[4];
#pragma unroll
    for (int j = 0; j < 4; ++j)
        if (j < m) {
            s[j] = clampi(ld_idx(ei, (long long)base + j, i64), 0, N - 1);
            d[j] = clampi(ld_idx(ei, (long long)E + base + j, i64), 0, N - 1);
        }
#pragma unroll
    for (int j = 0; j < 4; ++j)
        if (j < m) { ws[j] = dis[s[j]]; wd[j] = dis[d[j]]; }
#pragma unroll
    for (int j = 0; j < 4; ++j)
        if (j < m) pos[j] = row_ptr[d[j]] + atomicAdd(&fillcnt[d[j]], 1);
#pragma unroll
    for (int j = 0; j < 4; ++j)
        if (j < m) csr[pos[j]] = make_int2(s[j], __float_as_int(ws[j] * wd[j]));
}

// ---------------- Layer-1 aggregation on bf16 x (64 feats) ----------------
// 2 nodes/wave (half-wave per node), lane covers 2 feats via uint; 4-wide edge unroll.

__global__ __launch_bounds__(256) void gnn_agg_x(const void* __restrict__ x,
                                                 const unsigned short* __restrict__ xconv,
                                                 const int* __restrict__ rp,
                                                 const int2* __restrict__ csr,
                                                 const float* __restrict__ dis,
                                                 const int* __restrict__ flags,
                                                 float* __restrict__ aggX, int N) {
    const unsigned int* tab = flags[0] ? (const unsigned int*)xconv : (const unsigned int*)x;
    int t = threadIdx.x;
    int lane = t & 63;
    int n = blockIdx.x * 8 + (t >> 6) * 2 + (lane >> 5);
    if (n >= N) return;
    int fl = lane & 31;                          // uint index within 32-uint row
    float dn = dis[n];
    float dn2 = dn * dn;
    unsigned int us = tab[(long long)n * 32 + fl];
    float a0 = bfl(us) * dn2, a1 = bfh(us) * dn2;
    int beg = rp[n], end = rp[n + 1];
    int e = beg;
    for (; e + 4 <= end; e += 4) {
        int2 c0 = csr[e], c1 = csr[e + 1], c2 = csr[e + 2], c3 = csr[e + 3];
        unsigned int u0 = tab[(long long)c0.x * 32 + fl];
        unsigned int u1 = tab[(long long)c1.x * 32 + fl];
        unsigned int u2 = tab[(long long)c2.x * 32 + fl];
        unsigned int u3 = tab[(long long)c3.x * 32 + fl];
        float w0 = __int_as_float(c0.y), w1 = __int_as_float(c1.y);
        float w2 = __int_as_float(c2.y), w3 = __int_as_float(c3.y);
        a0 = fmaf(w0, bfl(u0), a0); a1 = fmaf(w0, bfh(u0), a1);
        a0 = fmaf(w1, bfl(u1), a0); a1 = fmaf(w1, bfh(u1), a1);
        a0 = fmaf(w2, bfl(u2), a0); a1 = fmaf(w2, bfh(u2), a1);
        a0 = fmaf(w3, bfl(u3), a0); a1 = fmaf(w3, bfh(u3), a1);
    }
    for (; e < end; ++e) {
        int2 c = csr[e];
        unsigned int u = tab[(long long)c.x * 32 + fl];
        float w = __int_as_float(c.y);
        a0 = fmaf(w, bfl(u), a0); a1 = fmaf(w, bfh(u), a1);
    }
    *(float2*)(aggX + (long long)n * 64 + fl * 2) = make_float2(a0, a1);
}

// ---------------- Linear: out[N,128] = X[N,K] @ W[K,128]  (32 nodes/block) -------------

template <int K, bool RELU, bool OUTBF>
__global__ __launch_bounds__(256) void gnn_linear(const float* __restrict__ X,
                                                  const float* __restrict__ Wf,
                                                  const float* __restrict__ bias,
                                                  int N, void* __restrict__ out) {
    __shared__ float Wl[64 * 128];
    __shared__ float Xs[32 * K];
    const int t = threadIdx.x;
    const int nbase = blockIdx.x * 32;

#pragma unroll
    for (int it = 0; it < K / 32; ++it) {
        int i4 = t + it * 256;
        int n = nbase + (i4 * 4) / K;
        float4 v = make_float4(0.f, 0.f, 0.f, 0.f);
        if (n < N) v = ((const float4*)X)[(long long)nbase * (K / 4) + i4];
        ((float4*)Xs)[i4] = v;
    }

    const int fg = t & 31, ng = t >> 5;
    const int f0 = fg * 4, n0 = ng * 4;
    float4 acc[4];
#pragma unroll
    for (int j = 0; j < 4; ++j) acc[j] = make_float4(0.f, 0.f, 0.f, 0.f);

    for (int kc = 0; kc < K; kc += 64) {
        __syncthreads();
#pragma unroll
        for (int it = 0; it < 8; ++it) {
            int i4 = t + it * 256;
            ((float4*)Wl)[i4] = ((const float4*)(Wf + kc * 128))[i4];
        }
        __syncthreads();
#pragma unroll 4
        for (int k = 0; k < 64; ++k) {
            const float4 w = *(const float4*)&Wl[k * 128 + f0];
#pragma unroll
            for (int j = 0; j < 4; ++j) {
                float xv = Xs[(n0 + j) * K + kc + k];
                acc[j].x = fmaf(xv, w.x, acc[j].x);
                acc[j].y = fmaf(xv, w.y, acc[j].y);
                acc[j].z = fmaf(xv, w.z, acc[j].z);
                acc[j].w = fmaf(xv, w.w, acc[j].w);
            }
        }
    }

#pragma unroll
    for (int j = 0; j < 4; ++j) {
        int n = nbase + n0 + j;
        if (n >= N) continue;
        float4 a = acc[j];
        if (RELU) {
            const float4 b = *(const float4*)&bias[f0];
            a.x = fmaxf(a.x + b.x, 0.f);
            a.y = fmaxf(a.y + b.y, 0.f);
            a.z = fmaxf(a.z + b.z, 0.f);
            a.w = fmaxf(a.w + b.w, 0.f);
        }
        if (OUTBF) {
            uint2 u;
            u.x = (unsigned int)f2bf(a.x) | ((unsigned int)f2bf(a.y) << 16);
            u.y = (unsigned int)f2bf(a.z) | ((unsigned int)f2bf(a.w) << 16);
            *(uint2*)((unsigned short*)out + (long long)n * 128 + f0) = u;
        } else {
            *(float4*)((float*)out + (long long)n * 128 + f0) = a;
        }
    }
}

// ---------------- Layer-2 aggregation over bf16 rows (128 feats) ----------------
// 2 nodes/wave, lane covers 4 feats via uint2; 4-wide edge unroll.

__global__ __launch_bounds__(256) void gnn_agg_bf(const unsigned short* __restrict__ A2,
                                                  const int* __restrict__ rp,
                                                  const int2* __restrict__ csr,
                                                  const float* __restrict__ dis,
                                                  const float* __restrict__ bias,
                                                  float* __restrict__ outC, int N) {
    int t = threadIdx.x;
    int lane = t & 63;
    int n = blockIdx.x * 8 + (t >> 6) * 2 + (lane >> 5);
    if (n >= N) return;
    int fl = lane & 31;                          // uint2 index within row
    float dn = dis[n];
    float dn2 = dn * dn;
    uint2 us = *(const uint2*)(A2 + (long long)n * 128 + fl * 4);
    float a0 = bfl(us.x) * dn2, a1 = bfh(us.x) * dn2;
    float a2 = bfl(us.y) * dn2, a3 = bfh(us.y) * dn2;
    int beg = rp[n], end = rp[n + 1];
    int e = beg;
    for (; e + 4 <= end; e += 4) {
        int2 c0 = csr[e], c1 = csr[e + 1], c2 = csr[e + 2], c3 = csr[e + 3];
        uint2 u0 = *(const uint2*)(A2 + (long long)c0.x * 128 + fl * 4);
        uint2 u1 = *(const uint2*)(A2 + (long long)c1.x * 128 + fl * 4);
        uint2 u2 = *(const uint2*)(A2 + (long long)c2.x * 128 + fl * 4);
        uint2 u3 = *(const uint2*)(A2 + (long long)c3.x * 128 + fl * 4);
        float w0 = __int_as_float(c0.y), w1 = __int_as_float(c1.y);
        float w2 = __int_as_float(c2.y), w3 = __int_as_float(c3.y);
        a0 = fmaf(w0, bfl(u0.x), a0); a1 = fmaf(w0, bfh(u0.x), a1);
        a2 = fmaf(w0, bfl(u0.y), a2); a3 = fmaf(w0, bfh(u0.y), a3);
        a0 = fmaf(w1, bfl(u1.x), a0); a1 = fmaf(w1, bfh(u1.x), a1);
        a2 = fmaf(w1, bfl(u1.y), a2); a3 = fmaf(w1, bfh(u1.y), a3);
        a0 = fmaf(w2, bfl(u2.x), a0); a1 = fmaf(w2, bfh(u2.x), a1);
        a2 = fmaf(w2, bfl(u2.y), a2); a3 = fmaf(w2, bfh(u2.y), a3);
        a0 = fmaf(w3, bfl(u3.x), a0); a1 = fmaf(w3, bfh(u3.x), a1);
        a2 = fmaf(w3, bfl(u3.y), a2); a3 = fmaf(w3, bfh(u3.y), a3);
    }
    for (; e < end; ++e) {
        int2 c = csr[e];
        uint2 u = *(const uint2*)(A2 + (long long)c.x * 128 + fl * 4);
        float w = __int_as_float(c.y);
        a0 = fmaf(w, bfl(u.x), a0); a1 = fmaf(w, bfh(u.x), a1);
        a2 = fmaf(w, bfl(u.y), a2); a3 = fmaf(w, bfh(u.y), a3);
    }
    const float4 b = *(const float4*)&bias[fl * 4];
    float4 o;
    o.x = fmaxf(a0 + b.x, 0.f);
    o.y = fmaxf(a1 + b.y, 0.f);
    o.z = fmaxf(a2 + b.z, 0.f);
    o.w = fmaxf(a3 + b.w, 0.f);
    *(float4*)(outC + (long long)n * 128 + fl * 4) = o;
}

// ---------------- Pool (batch sorted): 32-node strips, atomic flush ----------------

#define PSTRIP 32
__global__ __launch_bounds__(128) void gnn_pool(const float* __restrict__ h,
                                                const int* __restrict__ batch,
                                                const int* __restrict__ flags,
                                                float* __restrict__ pooled,
                                                float* __restrict__ cntf, int N, int B) {
    int i64 = flags[1];
    int f = threadIdx.x;
    int n0 = blockIdx.x * PSTRIP;
    if (n0 >= N) return;
    int nend = min(n0 + PSTRIP, N);
    int cur = clampi(ld_idx(batch, n0, i64), 0, B - 1);
    float acc = 0.0f;
    float cc = 0.0f;
    for (int n = n0; n < nend; ++n) {
        int b = clampi(ld_idx(batch, n, i64), 0, B - 1);
        if (b != cur) {
            atomicAdd(&pooled[cur * 128 + f], acc);
            if (f == 0) atomicAdd(&cntf[cur], cc);
            acc = 0.0f; cc = 0.0f; cur = b;
        }
        acc += h[(long long)n * 128 + f];
        cc += 1.0f;
    }
    atomicAdd(&pooled[cur * 128 + f], acc);
    if (f == 0) atomicAdd(&cntf[cur], cc);
}

// ---------------- Fused head ----------------

__global__ __launch_bounds__(128) void gnn_head(const float* __restrict__ pooled,
                                                const float* __restrict__ cntf,
                                                const float* __restrict__ W3,
                                                const float* __restrict__ b3,
                                                const float* __restrict__ W4,
                                                const float* __restrict__ b4,
                                                const int* __restrict__ flags,
                                                void* __restrict__ outv) {
    __shared__ float xs[128];
    __shared__ float rs[128];
    int b = blockIdx.x, f = threadIdx.x;
    float c = fmaxf(cntf[b], 1.0f);
    xs[f] = pooled[b * 128 + f] / c;
    __syncthreads();
    float acc = b3[f];
    for (int k = 0; k < 128; ++k) acc = fmaf(xs[k], W3[k * 128 + f], acc);
    rs[f] = fmaxf(acc, 0.f);
    __syncthreads();
    if (f < 64) {
        float a2 = b4[f];
        for (int k = 0; k < 128; ++k) a2 = fmaf(rs[k], W4[k * 64 + f], a2);
        if (flags[0]) ((float*)outv)[b * 64 + f] = a2;
        else          ((unsigned short*)outv)[b * 64 + f] = f2bf(a2);
    }
}

// ---------------- Launch ----------------

extern "C" void kernel_launch(void* const* d_in, const int* in_sizes, int n_in,
                              void* d_out, int out_size, void* d_ws, size_t ws_size,
                              hipStream_t stream) {
    const void* x  = d_in[0];
    const int* ei  = (const int*)d_in[1];
    const int* bat = (const int*)d_in[2];

    const int N = in_sizes[0] / 64;    // 50000
    const int E = in_sizes[1] / 2;     // 800000
    const int B = out_size / 64;       // 64

    char* p = (char*)d_ws;
    auto alloc = [&](size_t bytes) { void* q = (void*)p; p += (bytes + 255) & ~(size_t)255; return q; };
    int*   flags    = (int*)alloc(256);
    float* wsW      = (float*)alloc((size_t)OTOT * 4);
    int*   degcnt   = (int*)alloc((size_t)N * 4);
    int*   fillcnt  = (int*)alloc((size_t)N * 4);
    float* dis      = (float*)alloc((size_t)N * 4);
    int*   row_ptr  = (int*)alloc((size_t)(N + 1) * 4);
    int*   sums     = (int*)alloc(1024);
    int2*  csr      = (int2*)alloc((size_t)E * 8);
    unsigned short* xb = (unsigned short*)alloc((size_t)N * 64 * 2);
    float* C2       = (float*)alloc((size_t)N * 128 * 4);   // aggX (Nx64) then final C2 (Nx128)
    float* H1       = (float*)alloc((size_t)N * 128 * 4);   // layer-1 output
    unsigned short* A2 = (unsigned short*)alloc((size_t)N * 128 * 2);
    float* pooled   = (float*)alloc((size_t)B * 128 * 4);
    float* cntf     = (float*)alloc((size_t)B * 4);
    (void)ws_size; (void)n_in;

    const int nbN = (N + 255) / 256;   // 196

    gnn_detect<<<1, 256, 0, stream>>>((const unsigned int*)d_in[3], ei, flags);
    gnn_zeroall<<<200, 256, 0, stream>>>(degcnt, fillcnt, pooled, cntf, N, B);
    gnn_convert_w<<<(OTOT + 255) / 256, 256, 0, stream>>>(d_in[3], d_in[4], d_in[5], d_in[6],
                                                          d_in[7], d_in[8], d_in[9], d_in[10],
                                                          flags, wsW);
    gnn_convert_x<<<(N * 64 + 255) / 256, 256, 0, stream>>>(x, flags, xb, N * 64);

    const int nE4 = (E + 1023) / 1024;
    gnn_hist<<<nE4, 256, 0, stream>>>(ei, E, N, flags, degcnt);
    gnn_scan1<<<nbN, 256, 0, stream>>>(degcnt, row_ptr, sums, dis, N);
    gnn_scan2<<<1, 256, 0, stream>>>(sums, nbN);
    gnn_scan3<<<nbN, 256, 0, stream>>>(row_ptr, sums, N, E);
    gnn_fill<<<nE4, 256, 0, stream>>>(ei, dis, row_ptr, fillcnt, csr, E, N, flags);

    const int nlin = (N + 31) / 32;
    const int nagg = (N + 7) / 8;

    // layer 1: aggX = A_hat @ x ; H1 = relu(aggX @ W1 + b1)
    gnn_agg_x<<<nagg, 256, 0, stream>>>(x, xb, row_ptr, csr, dis, flags, C2, N);
    gnn_linear<64, true, false><<<nlin, 256, 0, stream>>>(C2, wsW + OW1, wsW + OB1, N, (void*)H1);

    // layer 2: A2 = H1 @ W2 (bf16) ; C2 = relu(A_hat @ A2 + b2)
    gnn_linear<128, false, true><<<nlin, 256, 0, stream>>>(H1, wsW + OW2, wsW + OB2, N, (void*)A2);
    gnn_agg_bf<<<nagg, 256, 0, stream>>>(A2, row_ptr, csr, dis, wsW + OB2, C2, N);

    // pool + head
    gnn_pool<<<(N + PSTRIP - 1) / PSTRIP, 128, 0, stream>>>(C2, bat, flags, pooled, cntf, N, B);
    gnn_head<<<B, 128, 0, stream>>>(pooled, cntf, wsW + OW3, wsW + OB3,
                                    wsW + OW4, wsW + OB4, flags, d_out);
}

// Round 6
// 311.631 us; speedup vs baseline: 1.6821x; 1.0261x over previous
//
#include <hip/hip_runtime.h>

// ---------------- helpers ----------------

__device__ __forceinline__ float ldf(const void* p, long long i, int f32) {
    if (f32) return ((const float*)p)[i];
    unsigned int u = ((const unsigned short*)p)[i];
    return __uint_as_float(u << 16);
}
__device__ __forceinline__ float bfl(unsigned int u) { return __uint_as_float(u << 16); }
__device__ __forceinline__ float bfh(unsigned int u) { return __uint_as_float(u & 0xFFFF0000u); }
__device__ __forceinline__ int ld_idx(const int* p, long long i, int i64) {
    return i64 ? p[2 * i] : p[i];   // little-endian low word of int64
}
__device__ __forceinline__ unsigned short f2bf(float v) {
    unsigned int x = __float_as_uint(v);
    return (unsigned short)((x + 0x7FFFu + ((x >> 16) & 1u)) >> 16);  // RNE
}
__device__ __forceinline__ int clampi(int v, int lo, int hi) {
    return v < lo ? lo : (v > hi ? hi : v);
}

// ---------------- dtype detection ----------------
// flags[0]=1 f32 floats / 0 bf16 ; flags[1]=1 int64 / 0 int32

__global__ void gnn_detect(const unsigned int* __restrict__ w1_words,
                           const int* __restrict__ ei_words,
                           int* __restrict__ flags) {
    __shared__ int cnt;
    __shared__ int orred;
    int t = threadIdx.x;
    if (t == 0) { cnt = 0; orred = 0; }
    __syncthreads();
    int c = 0, o = 0;
    for (int i = t; i < 512; i += 256) {
        unsigned int e = (w1_words[i] >> 7) & 0xFFu;
        if (e >= 100 && e <= 140) c++;
    }
    for (int i = t; i < 4096; i += 256) o |= ei_words[2 * i + 1];
    atomicAdd(&cnt, c);
    atomicOr(&orred, o);
    __syncthreads();
    if (t == 0) {
        flags[0] = (cnt > 256) ? 0 : 1;
        flags[1] = (orred == 0) ? 1 : 0;
    }
}

// ---------------- weights layout (contiguous f32) ----------------
#define OW1 0
#define OB1 8192
#define OW2 8320
#define OB2 24704
#define OW3 24832
#define OB3 41216
#define OW4 41344
#define OB4 49536
#define OTOT 49600

// ---------------- fused prep: zero-init + weight convert + x convert ----------------

__global__ void gnn_prep(const void* W1, const void* b1, const void* W2, const void* b2,
                         const void* W3, const void* b3, const void* W4, const void* b4,
                         const void* x, const int* __restrict__ flags,
                         int* __restrict__ degcnt, int* __restrict__ fillcnt,
                         float* __restrict__ pooled, float* __restrict__ cntf,
                         float* __restrict__ wsW, unsigned short* __restrict__ xb,
                         int N, int B) {
    const int f32 = flags[0];
    const int i = blockIdx.x * 256 + threadIdx.x;
    const int stride = gridDim.x * 256;
    for (int j = i; j < N; j += stride) { degcnt[j] = 0; fillcnt[j] = 0; }
    for (int j = i; j < B * 128; j += stride) pooled[j] = 0.f;
    for (int j = i; j < B; j += stride) cntf[j] = 0.f;
    for (int j = i; j < OTOT; j += stride) {
        float v;
        if      (j < OB1) v = ldf(W1, j - OW1, f32);
        else if (j < OW2) v = ldf(b1, j - OB1, f32);
        else if (j < OB2) v = ldf(W2, j - OW2, f32);
        else if (j < OW3) v = ldf(b2, j - OB2, f32);
        else if (j < OB3) v = ldf(W3, j - OW3, f32);
        else if (j < OW4) v = ldf(b3, j - OB3, f32);
        else if (j < OB4) v = ldf(W4, j - OW4, f32);
        else              v = ldf(b4, j - OB4, f32);
        wsW[j] = v;
    }
    if (f32) {
        const float* xf = (const float*)x;
        for (int j = i; j < N * 64; j += stride) xb[j] = f2bf(xf[j]);
    }
}

// ---------------- CSR build ----------------
// hist: 4 edges/thread (atomic is fire-and-forget)

__global__ void gnn_hist(const int* __restrict__ ei, int E, int N,
                         const int* __restrict__ flags, int* __restrict__ degcnt) {
    int base = (blockIdx.x * 256 + threadIdx.x) * 4;
    if (base >= E) return;
    int i64 = flags[1];
    int m = min(4, E - base);
    int d[4];
#pragma unroll
    for (int j = 0; j < 4; ++j)
        if (j < m) d[j] = clampi(ld_idx(ei, (long long)E + base + j, i64), 0, N - 1);
#pragma unroll
    for (int j = 0; j < 4; ++j)
        if (j < m) atomicAdd(&degcnt[d[j]], 1);
}

// scan1 also produces dis = rsqrt(deg+1)
__global__ void gnn_scan1(const int* __restrict__ cnt, int* __restrict__ excl,
                          int* __restrict__ sums, float* __restrict__ dis, int N) {
    __shared__ int sh[256];
    int t = threadIdx.x;
    int i = blockIdx.x * 256 + t;
    int v = (i < N) ? cnt[i] : 0;
    sh[t] = v;
    __syncthreads();
    for (int off = 1; off < 256; off <<= 1) {
        int a = (t >= off) ? sh[t - off] : 0;
        __syncthreads();
        sh[t] += a;
        __syncthreads();
    }
    if (i < N) {
        excl[i] = sh[t] - v;
        dis[i] = rsqrtf((float)v + 1.0f);
    }
    if (t == 255) sums[blockIdx.x] = sh[255];
}

__global__ void gnn_scan2(int* __restrict__ sums, int nb) {
    __shared__ int sh[256];
    int t = threadIdx.x;
    int v = (t < nb) ? sums[t] : 0;
    sh[t] = v;
    __syncthreads();
    for (int off = 1; off < 256; off <<= 1) {
        int a = (t >= off) ? sh[t - off] : 0;
        __syncthreads();
        sh[t] += a;
        __syncthreads();
    }
    if (t < nb) sums[t] = sh[t] - v;
}

// row_ptr[d] computed on the fly = excl[d] + bsums[d>>8]
// fill: 1 edge/thread (atomic return value needed -> wave-count-driven), 2B entries.

template <bool SMALLN>
__global__ void gnn_fill(const int* __restrict__ ei, const int* __restrict__ excl,
                         const int* __restrict__ bsums, int* __restrict__ fillcnt,
                         void* __restrict__ csr, int E, int N,
                         const int* __restrict__ flags) {
    int e = blockIdx.x * 256 + threadIdx.x;
    if (e >= E) return;
    int i64 = flags[1];
    int s = clampi(ld_idx(ei, (long long)e, i64), 0, N - 1);
    int d = clampi(ld_idx(ei, (long long)E + e, i64), 0, N - 1);
    int rp = excl[d] + bsums[d >> 8];
    int pos = rp + atomicAdd(&fillcnt[d], 1);
    if (SMALLN) ((unsigned short*)csr)[pos] = (unsigned short)s;
    else        ((int*)csr)[pos] = s;
}

template <bool SMALLN>
__device__ __forceinline__ int csr_at(const void* csr, int e) {
    return SMALLN ? (int)((const unsigned short*)csr)[e] : ((const int*)csr)[e];
}

// ---------------- Layer-1 aggregation on bf16 x (64 feats) ----------------
// 2 nodes/wave (half-wave per node), lane covers 2 feats via uint; 4-wide edge unroll.
// norm recomputed on the fly: w = dis[s] * dis[n]  (f32, same value as before)

template <bool SMALLN>
__global__ __launch_bounds__(256) void gnn_agg_x(const void* __restrict__ x,
                                                 const unsigned short* __restrict__ xconv,
                                                 const int* __restrict__ excl,
                                                 const int* __restrict__ bsums,
                                                 const void* __restrict__ csr,
                                                 const float* __restrict__ dis,
                                                 const int* __restrict__ flags,
                                                 float* __restrict__ aggX, int N, int E) {
    const unsigned int* tab = flags[0] ? (const unsigned int*)xconv : (const unsigned int*)x;
    int t = threadIdx.x;
    int lane = t & 63;
    int n = blockIdx.x * 8 + (t >> 6) * 2 + (lane >> 5);
    if (n >= N) return;
    int fl = lane & 31;                          // uint index within 32-uint row
    float dn = dis[n];
    float dn2 = dn * dn;
    unsigned int us = tab[(long long)n * 32 + fl];
    float a0 = bfl(us) * dn2, a1 = bfh(us) * dn2;
    int beg = excl[n] + bsums[n >> 8];
    int end = (n + 1 < N) ? (excl[n + 1] + bsums[(n + 1) >> 8]) : E;
    int e = beg;
    for (; e + 4 <= end; e += 4) {
        int s0 = csr_at<SMALLN>(csr, e),     s1 = csr_at<SMALLN>(csr, e + 1);
        int s2 = csr_at<SMALLN>(csr, e + 2), s3 = csr_at<SMALLN>(csr, e + 3);
        float w0 = dis[s0], w1 = dis[s1], w2 = dis[s2], w3 = dis[s3];
        unsigned int u0 = tab[(long long)s0 * 32 + fl];
        unsigned int u1 = tab[(long long)s1 * 32 + fl];
        unsigned int u2 = tab[(long long)s2 * 32 + fl];
        unsigned int u3 = tab[(long long)s3 * 32 + fl];
        w0 *= dn; w1 *= dn; w2 *= dn; w3 *= dn;
        a0 = fmaf(w0, bfl(u0), a0); a1 = fmaf(w0, bfh(u0), a1);
        a0 = fmaf(w1, bfl(u1), a0); a1 = fmaf(w1, bfh(u1), a1);
        a0 = fmaf(w2, bfl(u2), a0); a1 = fmaf(w2, bfh(u2), a1);
        a0 = fmaf(w3, bfl(u3), a0); a1 = fmaf(w3, bfh(u3), a1);
    }
    for (; e < end; ++e) {
        int s = csr_at<SMALLN>(csr, e);
        float w = dis[s] * dn;
        unsigned int u = tab[(long long)s * 32 + fl];
        a0 = fmaf(w, bfl(u), a0); a1 = fmaf(w, bfh(u), a1);
    }
    *(float2*)(aggX + (long long)n * 64 + fl * 2) = make_float2(a0, a1);
}

// ---------------- Linear: out[N,128] = X[N,K] @ W[K,128]  (32 nodes/block) -------------

template <int K, bool RELU, bool OUTBF>
__global__ __launch_bounds__(256) void gnn_linear(const float* __restrict__ X,
                                                  const float* __restrict__ Wf,
                                                  const float* __restrict__ bias,
                                                  int N, void* __restrict__ out) {
    __shared__ float Wl[64 * 128];
    __shared__ float Xs[32 * K];
    const int t = threadIdx.x;
    const int nbase = blockIdx.x * 32;

#pragma unroll
    for (int it = 0; it < K / 32; ++it) {
        int i4 = t + it * 256;
        int n = nbase + (i4 * 4) / K;
        float4 v = make_float4(0.f, 0.f, 0.f, 0.f);
        if (n < N) v = ((const float4*)X)[(long long)nbase * (K / 4) + i4];
        ((float4*)Xs)[i4] = v;
    }

    const int fg = t & 31, ng = t >> 5;
    const int f0 = fg * 4, n0 = ng * 4;
    float4 acc[4];
#pragma unroll
    for (int j = 0; j < 4; ++j) acc[j] = make_float4(0.f, 0.f, 0.f, 0.f);

    for (int kc = 0; kc < K; kc += 64) {
        __syncthreads();
#pragma unroll
        for (int it = 0; it < 8; ++it) {
            int i4 = t + it * 256;
            ((float4*)Wl)[i4] = ((const float4*)(Wf + kc * 128))[i4];
        }
        __syncthreads();
#pragma unroll 4
        for (int k = 0; k < 64; ++k) {
            const float4 w = *(const float4*)&Wl[k * 128 + f0];
#pragma unroll
            for (int j = 0; j < 4; ++j) {
                float xv = Xs[(n0 + j) * K + kc + k];
                acc[j].x = fmaf(xv, w.x, acc[j].x);
                acc[j].y = fmaf(xv, w.y, acc[j].y);
                acc[j].z = fmaf(xv, w.z, acc[j].z);
                acc[j].w = fmaf(xv, w.w, acc[j].w);
            }
        }
    }

#pragma unroll
    for (int j = 0; j < 4; ++j) {
        int n = nbase + n0 + j;
        if (n >= N) continue;
        float4 a = acc[j];
        if (RELU) {
            const float4 b = *(const float4*)&bias[f0];
            a.x = fmaxf(a.x + b.x, 0.f);
            a.y = fmaxf(a.y + b.y, 0.f);
            a.z = fmaxf(a.z + b.z, 0.f);
            a.w = fmaxf(a.w + b.w, 0.f);
        }
        if (OUTBF) {
            uint2 u;
            u.x = (unsigned int)f2bf(a.x) | ((unsigned int)f2bf(a.y) << 16);
            u.y = (unsigned int)f2bf(a.z) | ((unsigned int)f2bf(a.w) << 16);
            *(uint2*)((unsigned short*)out + (long long)n * 128 + f0) = u;
        } else {
            *(float4*)((float*)out + (long long)n * 128 + f0) = a;
        }
    }
}

// ---------------- Layer-2 aggregation over bf16 rows (128 feats) ----------------

template <bool SMALLN>
__global__ __launch_bounds__(256) void gnn_agg_bf(const unsigned short* __restrict__ A2,
                                                  const int* __restrict__ excl,
                                                  const int* __restrict__ bsums,
                                                  const void* __restrict__ csr,
                                                  const float* __restrict__ dis,
                                                  const float* __restrict__ bias,
                                                  float* __restrict__ outC, int N, int E) {
    int t = threadIdx.x;
    int lane = t & 63;
    int n = blockIdx.x * 8 + (t >> 6) * 2 + (lane >> 5);
    if (n >= N) return;
    int fl = lane & 31;                          // uint2 index within row
    float dn = dis[n];
    float dn2 = dn * dn;
    uint2 us = *(const uint2*)(A2 + (long long)n * 128 + fl * 4);
    float a0 = bfl(us.x) * dn2, a1 = bfh(us.x) * dn2;
    float a2 = bfl(us.y) * dn2, a3 = bfh(us.y) * dn2;
    int beg = excl[n] + bsums[n >> 8];
    int end = (n + 1 < N) ? (excl[n + 1] + bsums[(n + 1) >> 8]) : E;
    int e = beg;
    for (; e + 4 <= end; e += 4) {
        int s0 = csr_at<SMALLN>(csr, e),     s1 = csr_at<SMALLN>(csr, e + 1);
        int s2 = csr_at<SMALLN>(csr, e + 2), s3 = csr_at<SMALLN>(csr, e + 3);
        float w0 = dis[s0], w1 = dis[s1], w2 = dis[s2], w3 = dis[s3];
        uint2 u0 = *(const uint2*)(A2 + (long long)s0 * 128 + fl * 4);
        uint2 u1 = *(const uint2*)(A2 + (long long)s1 * 128 + fl * 4);
        uint2 u2 = *(const uint2*)(A2 + (long long)s2 * 128 + fl * 4);
        uint2 u3 = *(const uint2*)(A2 + (long long)s3 * 128 + fl * 4);
        w0 *= dn; w1 *= dn; w2 *= dn; w3 *= dn;
        a0 = fmaf(w0, bfl(u0.x), a0); a1 = fmaf(w0, bfh(u0.x), a1);
        a2 = fmaf(w0, bfl(u0.y), a2); a3 = fmaf(w0, bfh(u0.y), a3);
        a0 = fmaf(w1, bfl(u1.x), a0); a1 = fmaf(w1, bfh(u1.x), a1);
        a2 = fmaf(w1, bfl(u1.y), a2); a3 = fmaf(w1, bfh(u1.y), a3);
        a0 = fmaf(w2, bfl(u2.x), a0); a1 = fmaf(w2, bfh(u2.x), a1);
        a2 = fmaf(w2, bfl(u2.y), a2); a3 = fmaf(w2, bfh(u2.y), a3);
        a0 = fmaf(w3, bfl(u3.x), a0); a1 = fmaf(w3, bfh(u3.x), a1);
        a2 = fmaf(w3, bfl(u3.y), a2); a3 = fmaf(w3, bfh(u3.y), a3);
    }
    for (; e < end; ++e) {
        int s = csr_at<SMALLN>(csr, e);
        float w = dis[s] * dn;
        uint2 u = *(const uint2*)(A2 + (long long)s * 128 + fl * 4);
        a0 = fmaf(w, bfl(u.x), a0); a1 = fmaf(w, bfh(u.x), a1);
        a2 = fmaf(w, bfl(u.y), a2); a3 = fmaf(w, bfh(u.y), a3);
    }
    const float4 b = *(const float4*)&bias[fl * 4];
    float4 o;
    o.x = fmaxf(a0 + b.x, 0.f);
    o.y = fmaxf(a1 + b.y, 0.f);
    o.z = fmaxf(a2 + b.z, 0.f);
    o.w = fmaxf(a3 + b.w, 0.f);
    *(float4*)(outC + (long long)n * 128 + fl * 4) = o;
}

// ---------------- Pool (batch sorted): 32-node strips, atomic flush ----------------

#define PSTRIP 32
__global__ __launch_bounds__(128) void gnn_pool(const float* __restrict__ h,
                                                const int* __restrict__ batch,
                                                const int* __restrict__ flags,
                                                float* __restrict__ pooled,
                                                float* __restrict__ cntf, int N, int B) {
    int i64 = flags[1];
    int f = threadIdx.x;
    int n0 = blockIdx.x * PSTRIP;
    if (n0 >= N) return;
    int nend = min(n0 + PSTRIP, N);
    int cur = clampi(ld_idx(batch, n0, i64), 0, B - 1);
    float acc = 0.0f;
    float cc = 0.0f;
    for (int n = n0; n < nend; ++n) {
        int b = clampi(ld_idx(batch, n, i64), 0, B - 1);
        if (b != cur) {
            atomicAdd(&pooled[cur * 128 + f], acc);
            if (f == 0) atomicAdd(&cntf[cur], cc);
            acc = 0.0f; cc = 0.0f; cur = b;
        }
        acc += h[(long long)n * 128 + f];
        cc += 1.0f;
    }
    atomicAdd(&pooled[cur * 128 + f], acc);
    if (f == 0) atomicAdd(&cntf[cur], cc);
}

// ---------------- Fused head ----------------

__global__ __launch_bounds__(128) void gnn_head(const float* __restrict__ pooled,
                                                const float* __restrict__ cntf,
                                                const float* __restrict__ W3,
                                                const float* __restrict__ b3,
                                                const float* __restrict__ W4,
                                                const float* __restrict__ b4,
                                                const int* __restrict__ flags,
                                                void* __restrict__ outv) {
    __shared__ float xs[128];
    __shared__ float rs[128];
    int b = blockIdx.x, f = threadIdx.x;
    float c = fmaxf(cntf[b], 1.0f);
    xs[f] = pooled[b * 128 + f] / c;
    __syncthreads();
    float acc = b3[f];
    for (int k = 0; k < 128; ++k) acc = fmaf(xs[k], W3[k * 128 + f], acc);
    rs[f] = fmaxf(acc, 0.f);
    __syncthreads();
    if (f < 64) {
        float a2 = b4[f];
        for (int k = 0; k < 128; ++k) a2 = fmaf(rs[k], W4[k * 64 + f], a2);
        if (flags[0]) ((float*)outv)[b * 64 + f] = a2;
        else          ((unsigned short*)outv)[b * 64 + f] = f2bf(a2);
    }
}

// ---------------- Launch ----------------

extern "C" void kernel_launch(void* const* d_in, const int* in_sizes, int n_in,
                              void* d_out, int out_size, void* d_ws, size_t ws_size,
                              hipStream_t stream) {
    const void* x  = d_in[0];
    const int* ei  = (const int*)d_in[1];
    const int* bat = (const int*)d_in[2];

    const int N = in_sizes[0] / 64;    // 50000
    const int E = in_sizes[1] / 2;     // 800000
    const int B = out_size / 64;       // 64
    const bool smalln = (N < 65536);

    char* p = (char*)d_ws;
    auto alloc = [&](size_t bytes) { void* q = (void*)p; p += (bytes + 255) & ~(size_t)255; return q; };
    int*   flags    = (int*)alloc(256);
    float* wsW      = (float*)alloc((size_t)OTOT * 4);
    int*   degcnt   = (int*)alloc((size_t)N * 4);
    int*   fillcnt  = (int*)alloc((size_t)N * 4);
    float* dis      = (float*)alloc((size_t)N * 4);
    int*   excl     = (int*)alloc((size_t)N * 4);
    int*   bsums    = (int*)alloc(1024);
    void*  csr      = alloc((size_t)E * (smalln ? 2 : 4));
    unsigned short* xb = (unsigned short*)alloc((size_t)N * 64 * 2);
    float* C2       = (float*)alloc((size_t)N * 128 * 4);   // aggX (Nx64) then final C2 (Nx128)
    float* H1       = (float*)alloc((size_t)N * 128 * 4);   // layer-1 output
    unsigned short* A2 = (unsigned short*)alloc((size_t)N * 128 * 2);
    float* pooled   = (float*)alloc((size_t)B * 128 * 4);
    float* cntf     = (float*)alloc((size_t)B * 4);
    (void)ws_size; (void)n_in;

    const int nbN = (N + 255) / 256;   // 196 (fits single-block scan2)

    gnn_detect<<<1, 256, 0, stream>>>((const unsigned int*)d_in[3], ei, flags);
    gnn_prep<<<512, 256, 0, stream>>>(d_in[3], d_in[4], d_in[5], d_in[6],
                                      d_in[7], d_in[8], d_in[9], d_in[10],
                                      x, flags, degcnt, fillcnt, pooled, cntf,
                                      wsW, xb, N, B);

    gnn_hist<<<(E + 1023) / 1024, 256, 0, stream>>>(ei, E, N, flags, degcnt);
    gnn_scan1<<<nbN, 256, 0, stream>>>(degcnt, excl, bsums, dis, N);
    gnn_scan2<<<1, 256, 0, stream>>>(bsums, nbN);
    if (smalln)
        gnn_fill<true><<<(E + 255) / 256, 256, 0, stream>>>(ei, excl, bsums, fillcnt, csr, E, N, flags);
    else
        gnn_fill<false><<<(E + 255) / 256, 256, 0, stream>>>(ei, excl, bsums, fillcnt, csr, E, N, flags);

    const int nlin = (N + 31) / 32;
    const int nagg = (N + 7) / 8;

    // layer 1: aggX = A_hat @ x ; H1 = relu(aggX @ W1 + b1)
    if (smalln)
        gnn_agg_x<true><<<nagg, 256, 0, stream>>>(x, xb, excl, bsums, csr, dis, flags, C2, N, E);
    else
        gnn_agg_x<false><<<nagg, 256, 0, stream>>>(x, xb, excl, bsums, csr, dis, flags, C2, N, E);
    gnn_linear<64, true, false><<<nlin, 256, 0, stream>>>(C2, wsW + OW1, wsW + OB1, N, (void*)H1);

    // layer 2: A2 = H1 @ W2 (bf16) ; C2 = relu(A_hat @ A2 + b2)
    gnn_linear<128, false, true><<<nlin, 256, 0, stream>>>(H1, wsW + OW2, wsW + OB2, N, (void*)A2);
    if (smalln)
        gnn_agg_bf<true><<<nagg, 256, 0, stream>>>(A2, excl, bsums, csr, dis, wsW + OB2, C2, N, E);
    else
        gnn_agg_bf<false><<<nagg, 256, 0, stream>>>(A2, excl, bsums, csr, dis, wsW + OB2, C2, N, E);

    // pool + head
    gnn_pool<<<(N + PSTRIP - 1) / PSTRIP, 128, 0, stream>>>(C2, bat, flags, pooled, cntf, N, B);
    gnn_head<<<B, 128, 0, stream>>>(pooled, cntf, wsW + OW3, wsW + OB3,
                                    wsW + OW4, wsW + OB4, flags, d_out);
}